// Round 3
// baseline (631.504 us; speedup 1.0000x reference)
//
#include <hip/hip_runtime.h>
#include <stdint.h>

typedef unsigned short ushort_t;
typedef __attribute__((ext_vector_type(8))) short short8;       // 8 x bf16 (MFMA A/B frag)
typedef __attribute__((ext_vector_type(4))) float floatx4;      // 16x16 C frag / 16B fp32
typedef __attribute__((ext_vector_type(16))) float floatx16;    // 32x32 C frag
typedef __attribute__((ext_vector_type(4))) unsigned int u32x4; // 16B vector

__device__ __forceinline__ float bf2f(ushort_t u) {
    union { unsigned int i; float f; } v; v.i = ((unsigned int)u) << 16; return v.f;
}
__device__ __forceinline__ ushort_t f2bf(float f) {
    union { float ff; unsigned int i; } v; v.ff = f;
    unsigned int x = v.i;
    return (ushort_t)((x + 0x7fffu + ((x >> 16) & 1u)) >> 16);  // RNE
}
__device__ __forceinline__ float gelu_f(float v) {
    float u = v * (0.7978845608f + 0.0356774081f * v * v);
    float e = __expf(2.f * u);
    float th = 1.f - 2.f / (e + 1.f);    // tanh(u)
    return 0.5f * v * (1.f + th);
}
#define LDS_ROUNDTRIP_FENCE() __asm__ volatile("s_waitcnt lgkmcnt(0)" ::: "memory")
// LDS-only barrier: orders ds ops across the workgroup WITHOUT draining vmcnt.
// Safe whenever cross-wave data flows through LDS only (global loads are
// consumed via same-wave register deps, which the compiler waits on).
// Validated correct in the R1 (v5) run.
#define BAR_SYNC_LDS() __asm__ volatile("s_waitcnt lgkmcnt(0)\n\ts_barrier" ::: "memory")

// Padded weight-prep strides (odd dword counts -> conflict-free ds_read_b128):
// w1p: [16][64][266] bf16 (row 266 ushort = 133 dwords, gcd(133,32)=1)
// w2p: [16][256][74] bf16 (row  74 ushort =  37 dwords, gcd(37,32)=1)
#define W1_STRIDE 266
#define W1_CHUNK  17024   // 64*266 ushorts = 34048 B = 2128 u32x4 (8*256 + 80)
#define W2_STRIDE 74
#define W2_CHUNK  18944   // 256*74 ushorts = 37888 B = 2368 u32x4 (9*256 + 64)

// ================= prep_k: ln1 (blocks 0..1023) + all weight preps (1024..1663) ==========
__global__ __launch_bounds__(256) void prep_k(
    const float* __restrict__ x, const float* __restrict__ n1g, const float* __restrict__ n1b,
    ushort_t* __restrict__ xn,
    const float* __restrict__ qkv_r, ushort_t* __restrict__ wqkvT_r,
    const float* __restrict__ qkv_a, ushort_t* __restrict__ wqkvT_a,
    const float* __restrict__ pr_w,  ushort_t* __restrict__ wpT_r,
    const float* __restrict__ pa_w,  ushort_t* __restrict__ wpT_a,
    const float* __restrict__ w1,    ushort_t* __restrict__ w1p,
    const float* __restrict__ w2,    ushort_t* __restrict__ w2p)
{
    __shared__ __align__(16) char pshm[33792];
    const int t = threadIdx.x;
    int b = blockIdx.x;
    if (b < 1024) {
        // ---- LN1 + NCHW(fp32) -> NHWC(bf16) ----
        ushort_t* tile = (ushort_t*)pshm;    // [64][264]
        const int p0 = b * 64;
        {
            const int pg = t & 15, cb = t >> 4;
            for (int it = 0; it < 16; ++it) {
                int c = cb + 16 * it;
                floatx4 v = *(const floatx4*)(x + (size_t)c * 65536 + p0 + pg * 4);
                #pragma unroll
                for (int k = 0; k < 4; ++k) tile[(pg * 4 + k) * 264 + c] = f2bf(v[k]);
            }
        }
        __syncthreads();
        const int pix = t >> 2, part = t & 3;
        float vals[64];
        float s = 0.f, ss = 0.f;
        #pragma unroll
        for (int k = 0; k < 64; ++k) {
            float v = bf2f(tile[pix * 264 + part * 64 + k]);
            vals[k] = v; s += v; ss += v * v;
        }
        s  += __shfl_xor(s, 1);  s  += __shfl_xor(s, 2);
        ss += __shfl_xor(ss, 1); ss += __shfl_xor(ss, 2);
        float mean = s * (1.f / 256.f);
        float rstd = rsqrtf(ss * (1.f / 256.f) - mean * mean + 1e-5f);
        size_t obase = (size_t)(p0 + pix) * 256 + part * 64;
        #pragma unroll
        for (int k8 = 0; k8 < 8; ++k8) {
            alignas(16) ushort_t o8[8];
            #pragma unroll
            for (int k = 0; k < 8; ++k) {
                int c = part * 64 + k8 * 8 + k;
                o8[k] = f2bf((vals[k8 * 8 + k] - mean) * rstd * n1g[c] + n1b[c]);
            }
            *(u32x4*)(xn + obase + k8 * 8) = *(const u32x4*)o8;
        }
        return;
    }
    b -= 1024;
    if (b < 512) {
        // ---- simple transposes fp32 [R][C] -> bf16 [C][R] ----
        const float* src; ushort_t* dst; int R, C, bi;
        if (b < 192)      { src = qkv_r; dst = wqkvT_r; R = 128; C = 384; bi = b;       }
        else if (b < 384) { src = qkv_a; dst = wqkvT_a; R = 128; C = 384; bi = b - 192; }
        else if (b < 448) { src = pr_w;  dst = wpT_r;   R = 128; C = 128; bi = b - 384; }
        else              { src = pa_w;  dst = wpT_a;   R = 128; C = 128; bi = b - 448; }
        int nbx = C / 16;
        int c0 = (bi % nbx) * 16, r0 = (bi / nbx) * 16;
        float* ts = (float*)pshm;    // [16][17]
        int tx = t & 15, ty = t >> 4;
        ts[ty * 17 + tx] = src[(size_t)(r0 + ty) * C + (c0 + tx)];
        __syncthreads();
        dst[(size_t)(c0 + ty) * R + (r0 + tx)] = f2bf(ts[tx * 17 + ty]);
        return;
    }
    b -= 512;
    float* s = (float*)pshm;   // [64][65]
    if (b < 64) {
        // ---- w1prep: w1 fp32 [256][1024] -> [16][64][266] (padded) ----
        const int ch = b & 15, k0 = (b >> 4) * 64;
        {
            int nn = t & 63, kr = t >> 6;
            for (int j = 0; j < 16; ++j) {
                int kk = j * 4 + kr;
                s[kk * 65 + nn] = w1[(size_t)(k0 + kk) * 1024 + ch * 64 + nn];
            }
        }
        __syncthreads();
        {
            int kk = t & 63, nr = t >> 6;
            for (int j = 0; j < 16; ++j) {
                int n2 = j * 4 + nr;
                w1p[(size_t)ch * W1_CHUNK + n2 * W1_STRIDE + k0 + kk] = f2bf(s[kk * 65 + n2]);
            }
        }
        return;
    }
    b -= 64;
    {
        // ---- w2prep: w2 fp32 [1024][256] -> [16][256][74] (padded) ----
        const int ch = b & 15, n0 = (b >> 4) * 64;
        {
            int nn = t & 63, kr = t >> 6;
            for (int j = 0; j < 16; ++j) {
                int kk = j * 4 + kr;
                s[kk * 65 + nn] = w2[(size_t)(ch * 64 + kk) * 256 + n0 + nn];
            }
        }
        __syncthreads();
        {
            int kk = t & 63, nr = t >> 6;
            for (int j = 0; j < 16; ++j) {
                int n2 = j * 4 + nr;
                w2p[(size_t)ch * W2_CHUNK + (n0 + n2) * W2_STRIDE + kk] = f2bf(s[kk * 65 + n2]);
            }
        }
    }
}

// ================= attn_k: one window per block (unchanged) =================
__global__ __launch_bounds__(256, 2) void attn_k(
    const ushort_t* __restrict__ xn,
    const ushort_t* __restrict__ wqkvT_r, const ushort_t* __restrict__ wpT_r,
    const float* __restrict__ bp_r, const float* __restrict__ table_r,
    const ushort_t* __restrict__ wqkvT_a, const ushort_t* __restrict__ wpT_a,
    const float* __restrict__ bp_a, const float* __restrict__ table_a,
    ushort_t* __restrict__ bout)
{
    __shared__ __align__(16) char smem_raw[71680];
    ushort_t* xw_s = (ushort_t*)smem_raw;                   // [64][136]
    ushort_t* q_s  = (ushort_t*)(smem_raw + 17408);         // q [64][136] / P [2][64][72]
    ushort_t* k_s  = (ushort_t*)(smem_raw + 35840);         // k [64][136] / O [64][136]
    ushort_t* v_s  = (ushort_t*)(smem_raw + 53248);         // vT [128][72]

    const int br  = blockIdx.y;
    const int wid = blockIdx.x;
    const int t = threadIdx.x;
    const int wv = t >> 6, lane = t & 63, l15 = lane & 15, quad = lane >> 4;

    const int WwLog = br ? 4 : 2;
    const int WhLog = br ? 2 : 4;
    const int nWxLog = 8 - WwLog;
    const int wx = wid & ((1 << nWxLog) - 1);
    const int wy = wid >> nWxLog;
    const int chOff = br ? 128 : 0;
    const int WwM1 = (1 << WwLog) - 1, WhM1 = (1 << WhLog) - 1;
    const int biasMul = 2 * (1 << WwLog) - 1;
    const ushort_t* wqkvT = br ? wqkvT_a : wqkvT_r;
    const ushort_t* wpT   = br ? wpT_a   : wpT_r;
    const float* bp    = br ? bp_a    : bp_r;
    const float* table = br ? table_a : table_r;

    auto tok2p = [&](int n) -> int {
        int i = n >> WwLog, j = n & WwM1;
        return ((wy << WhLog) + i) * 256 + (wx << WwLog) + j;
    };

    {
        int tok = t >> 2, seg = t & 3;
        const ushort_t* src = xn + (size_t)tok2p(tok) * 256 + chOff + seg * 32;
        ushort_t* dst = xw_s + tok * 136 + seg * 32;
        *(u32x4*)(dst)      = *(const u32x4*)(src);
        *(u32x4*)(dst + 8)  = *(const u32x4*)(src + 8);
        *(u32x4*)(dst + 16) = *(const u32x4*)(src + 16);
        *(u32x4*)(dst + 24) = *(const u32x4*)(src + 24);
    }
    __syncthreads();

    {
        short8 afrag[4];
        #pragma unroll
        for (int kt = 0; kt < 4; ++kt)
            afrag[kt] = *(const short8*)(xw_s + (16 * wv + l15) * 136 + kt * 32 + quad * 8);
        for (int nt = 0; nt < 24; ++nt) {
            floatx4 acc = {0.f, 0.f, 0.f, 0.f};
            const ushort_t* wb = wqkvT + (size_t)(nt * 16 + l15) * 128 + quad * 8;
            #pragma unroll
            for (int kt = 0; kt < 4; ++kt)
                acc = __builtin_amdgcn_mfma_f32_16x16x32_bf16(afrag[kt],
                        *(const short8*)(wb + kt * 32), acc, 0, 0, 0);
            int ncol = nt * 16 + l15;
            #pragma unroll
            for (int r = 0; r < 4; ++r) {
                int row = 16 * wv + quad * 4 + r;
                ushort_t val = f2bf(acc[r]);
                if (ncol < 128)      q_s[row * 136 + ncol] = val;
                else if (ncol < 256) k_s[row * 136 + (ncol - 128)] = val;
                else                 v_s[(ncol - 256) * 72 + row] = val;
            }
        }
    }
    __syncthreads();

    float pvals[2][4][4];
    #pragma unroll
    for (int head = 0; head < 2; ++head) {
        floatx4 sacc[4];
        #pragma unroll
        for (int nt = 0; nt < 4; ++nt) sacc[nt] = floatx4{0.f, 0.f, 0.f, 0.f};
        #pragma unroll
        for (int kt = 0; kt < 2; ++kt) {
            short8 aq = *(const short8*)(q_s + (16 * wv + l15) * 136 + head * 64 + kt * 32 + quad * 8);
            #pragma unroll
            for (int nt = 0; nt < 4; ++nt) {
                short8 bk = *(const short8*)(k_s + (nt * 16 + l15) * 136 + head * 64 + kt * 32 + quad * 8);
                sacc[nt] = __builtin_amdgcn_mfma_f32_16x16x32_bf16(aq, bk, sacc[nt], 0, 0, 0);
            }
        }
        #pragma unroll
        for (int r = 0; r < 4; ++r) {
            int qrow = 16 * wv + quad * 4 + r;
            int iq = qrow >> WwLog, jq = qrow & WwM1;
            float v[4], mx = -1e30f;
            #pragma unroll
            for (int nt = 0; nt < 4; ++nt) {
                int kcol = nt * 16 + l15;
                int ik = kcol >> WwLog, jk = kcol & WwM1;
                int idx = (iq - ik + WhM1) * biasMul + (jq - jk + WwM1);
                v[nt] = sacc[nt][r] * 0.125f + table[idx * 2 + head];
                mx = fmaxf(mx, v[nt]);
            }
            mx = fmaxf(mx, __shfl_xor(mx, 1)); mx = fmaxf(mx, __shfl_xor(mx, 2));
            mx = fmaxf(mx, __shfl_xor(mx, 4)); mx = fmaxf(mx, __shfl_xor(mx, 8));
            float e[4], sm = 0.f;
            #pragma unroll
            for (int nt = 0; nt < 4; ++nt) { e[nt] = __expf(v[nt] - mx); sm += e[nt]; }
            sm += __shfl_xor(sm, 1); sm += __shfl_xor(sm, 2);
            sm += __shfl_xor(sm, 4); sm += __shfl_xor(sm, 8);
            float inv = 1.f / sm;
            #pragma unroll
            for (int nt = 0; nt < 4; ++nt) pvals[head][nt][r] = e[nt] * inv;
        }
    }
    __syncthreads();

    {
        ushort_t* p_s = q_s;
        #pragma unroll
        for (int head = 0; head < 2; ++head)
            #pragma unroll
            for (int nt = 0; nt < 4; ++nt)
                #pragma unroll
                for (int r = 0; r < 4; ++r) {
                    int row = 16 * wv + quad * 4 + r;
                    p_s[(head * 64 + row) * 72 + nt * 16 + l15] = f2bf(pvals[head][nt][r]);
                }
    }
    LDS_ROUNDTRIP_FENCE();
    {
        const ushort_t* p_s = q_s;
        ushort_t* o_s = k_s;
        #pragma unroll
        for (int head = 0; head < 2; ++head) {
            short8 ap[2];
            #pragma unroll
            for (int kt = 0; kt < 2; ++kt)
                ap[kt] = *(const short8*)(p_s + (head * 64 + 16 * wv + l15) * 72 + kt * 32 + quad * 8);
            #pragma unroll
            for (int nt = 0; nt < 4; ++nt) {
                floatx4 acc = {0.f, 0.f, 0.f, 0.f};
                #pragma unroll
                for (int kt = 0; kt < 2; ++kt) {
                    short8 bv = *(const short8*)(v_s + (head * 64 + nt * 16 + l15) * 72 + kt * 32 + quad * 8);
                    acc = __builtin_amdgcn_mfma_f32_16x16x32_bf16(ap[kt], bv, acc, 0, 0, 0);
                }
                #pragma unroll
                for (int r = 0; r < 4; ++r)
                    o_s[(16 * wv + quad * 4 + r) * 136 + head * 64 + nt * 16 + l15] = f2bf(acc[r]);
            }
        }
    }
    __syncthreads();

    {
        const ushort_t* o_s = k_s;
        short8 ao[4];
        #pragma unroll
        for (int kt = 0; kt < 4; ++kt)
            ao[kt] = *(const short8*)(o_s + (16 * wv + l15) * 136 + kt * 32 + quad * 8);
        #pragma unroll
        for (int nt = 0; nt < 8; ++nt) {
            floatx4 acc = {0.f, 0.f, 0.f, 0.f};
            const ushort_t* wb = wpT + (size_t)(nt * 16 + l15) * 128 + quad * 8;
            #pragma unroll
            for (int kt = 0; kt < 4; ++kt)
                acc = __builtin_amdgcn_mfma_f32_16x16x32_bf16(ao[kt],
                        *(const short8*)(wb + kt * 32), acc, 0, 0, 0);
            int col = nt * 16 + l15;
            float bpv = bp[col];
            #pragma unroll
            for (int r = 0; r < 4; ++r) {
                int row = 16 * wv + quad * 4 + r;
                float res = acc[r] + bpv + bf2f(xw_s[row * 136 + col]);
                bout[(size_t)tok2p(row) * 256 + chOff + col] = f2bf(res);
            }
        }
    }
}

// ================= mlp_k v7: separate padded W1/W2 buffers, 2 LDS barriers/chunk =========
// LDS 81408 B (2 blocks/CU):
//   W1buf [64][266] @0      (34048)  <- also startup tile [64][264] overlay
//   W2buf [256][74] @34048  (37888)
//   hbuf  [64][74]  @71936  (9472)
//   ot_s  [256][74] @0      (37888, epilogue overlay over W1buf+W2buf head)
// Odd-dword row strides (133 / 37) -> conflict-free ds_read_b128.
// Chunk schedule (BAR = lgkm-only, weight prefetch loads survive barriers):
//   top:    issue w1[ch+1] global->reg          (hidden under GEMM1)
//   GEMM1(ch): W1buf -> hbuf
//   BAR1    (hbuf visible; W1buf reads done)
//   write w1reg->W1buf; issue w2[ch+1]->reg     (hidden under GEMM2)
//   GEMM2(ch): W2buf + hbuf -> oacc
//   BAR2    (W2buf reads done; w1 writes drained)
//   write w2reg->W2buf                          (drained by next BAR1)
// x2 residual recomputed in the store loop from x + bout (L1/L2-resident).
__global__ __launch_bounds__(256, 2) void mlp_k(
    const float* __restrict__ x,          // NCHW fp32
    const ushort_t* __restrict__ bout,    // NHWC bf16
    const float* __restrict__ g2, const float* __restrict__ b2,
    const ushort_t* __restrict__ w1p, const float* __restrict__ b1,
    const ushort_t* __restrict__ w2p, const float* __restrict__ bm2,
    float* __restrict__ out)
{
    __shared__ __align__(16) char smem_raw[81408];
    ushort_t* w1b  = (ushort_t*)smem_raw;               // [64][266]
    ushort_t* w2b  = (ushort_t*)(smem_raw + 34048);     // [256][74]
    ushort_t* hbuf = (ushort_t*)(smem_raw + 71936);     // [64][74]
    ushort_t* tile = (ushort_t*)smem_raw;               // [64][264] startup overlay
    ushort_t* ot_s = (ushort_t*)smem_raw;               // [256][74] epilogue overlay

    const int t = threadIdx.x;
    const int p0 = blockIdx.x * 64;
    const int wv = t >> 6, lane = t & 63, l31 = lane & 31, half = lane >> 5;

    {   // x fp32 NCHW tile -> tile bf16
        const int pg = t & 15, cb = t >> 4;
        for (int it = 0; it < 16; ++it) {
            int c = cb + 16 * it;
            floatx4 v = *(const floatx4*)(x + (size_t)c * 65536 + p0 + pg * 4);
            #pragma unroll
            for (int k = 0; k < 4; ++k) tile[(pg * 4 + k) * 264 + c] = f2bf(v[k]);
        }
    }
    BAR_SYNC_LDS();
    {   // x2 = x + bout; LN2 -> xn written IN PLACE into tile (each thread owns its cells)
        const int row = t >> 2, part = t & 3;
        float vals[64];
        float s = 0.f, ss = 0.f;
        const ushort_t* bpr = bout + (size_t)(p0 + row) * 256 + part * 64;
        ushort_t* xpr = tile + row * 264 + part * 64;
        #pragma unroll
        for (int k8 = 0; k8 < 8; ++k8) {
            u32x4 bv = *(const u32x4*)(bpr + k8 * 8);
            u32x4 xv = *(const u32x4*)(xpr + k8 * 8);
            const ushort_t* pb = (const ushort_t*)&bv;
            const ushort_t* px = (const ushort_t*)&xv;
            #pragma unroll
            for (int k = 0; k < 8; ++k) {
                float v = bf2f(px[k]) + bf2f(pb[k]);
                vals[k8 * 8 + k] = v; s += v; ss += v * v;
            }
        }
        s  += __shfl_xor(s, 1);  s  += __shfl_xor(s, 2);
        ss += __shfl_xor(ss, 1); ss += __shfl_xor(ss, 2);
        float mean = s * (1.f / 256.f);
        float rstd = rsqrtf(ss * (1.f / 256.f) - mean * mean + 1e-5f);
        const float* g2p = g2 + part * 64;
        const float* b2p = b2 + part * 64;
        #pragma unroll
        for (int k8 = 0; k8 < 8; ++k8) {
            alignas(16) ushort_t n8[8];
            #pragma unroll
            for (int k = 0; k < 8; ++k) {
                float v = vals[k8 * 8 + k];
                n8[k] = f2bf((v - mean) * rstd * g2p[k8 * 8 + k] + b2p[k8 * 8 + k]);
            }
            *(u32x4*)(xpr + k8 * 8) = *(const u32x4*)n8;
        }
    }
    BAR_SYNC_LDS();

    // GEMM1 wave tile: rows 32*g1m..+31, hidden cols 32*g1n..+31 of the 64-col chunk
    const int g1m = wv & 1, g1n = wv >> 1;
    // GEMM2 wave tiles: rows 32*g2m..+31, out cols g2nb + {0,32,64,96}
    const int g2m = wv & 1;
    const int g2nb = 128 * (wv >> 1);

    short8 afrag[16];    // xn rows (32) x K=256, register-resident
    #pragma unroll
    for (int ks = 0; ks < 16; ++ks)
        afrag[ks] = *(const short8*)(tile + (32 * g1m + l31) * 264 + ks * 16 + half * 8);

    u32x4* wb1 = (u32x4*)w1b;
    u32x4* wb2 = (u32x4*)w2b;
    u32x4 w1reg[9], w2reg[10];
    {   // prologue: load w1[0] (2128 u32x4) and w2[0] (2368 u32x4) into regs
        const u32x4* s1 = (const u32x4*)w1p;
        #pragma unroll
        for (int j = 0; j < 8; ++j) w1reg[j] = s1[j * 256 + t];
        if (t < 80) w1reg[8] = s1[2048 + t];
        const u32x4* s2 = (const u32x4*)w2p;
        #pragma unroll
        for (int j = 0; j < 9; ++j) w2reg[j] = s2[j * 256 + t];
        if (t < 64) w2reg[9] = s2[2304 + t];
    }
    BAR_SYNC_LDS();    // all afrag / tile reads done (tile dead)
    {
        #pragma unroll
        for (int j = 0; j < 8; ++j) wb1[j * 256 + t] = w1reg[j];
        if (t < 80) wb1[2048 + t] = w1reg[8];
        #pragma unroll
        for (int j = 0; j < 9; ++j) wb2[j * 256 + t] = w2reg[j];
        if (t < 64) wb2[2304 + t] = w2reg[9];
    }
    BAR_SYNC_LDS();    // W1buf = w1[0], W2buf = w2[0]

    floatx16 oacc[4];
    #pragma unroll
    for (int nt = 0; nt < 4; ++nt)
        #pragma unroll
        for (int i = 0; i < 16; ++i) oacc[nt][i] = 0.f;

    for (int ch = 0; ch < 16; ++ch) {
        if (ch < 15) {   // prefetch w1[ch+1] into regs (covered by GEMM1)
            const u32x4* s1 = (const u32x4*)(w1p + (size_t)(ch + 1) * W1_CHUNK);
            #pragma unroll
            for (int j = 0; j < 8; ++j) w1reg[j] = s1[j * 256 + t];
            if (t < 80) w1reg[8] = s1[2048 + t];
        }
        // ---- GEMM1: H-chunk = xn @ w1[ch], two interleaved accumulator chains
        floatx16 ha, hb;
        #pragma unroll
        for (int i = 0; i < 16; ++i) { ha[i] = 0.f; hb[i] = 0.f; }
        #pragma unroll
        for (int ks = 0; ks < 16; ks += 2) {
            short8 bf0 = *(const short8*)(w1b + (32 * g1n + l31) * W1_STRIDE + ks * 16 + half * 8);
            short8 bf1 = *(const short8*)(w1b + (32 * g1n + l31) * W1_STRIDE + ks * 16 + 16 + half * 8);
            ha = __builtin_amdgcn_mfma_f32_32x32x16_bf16(afrag[ks], bf0, ha, 0, 0, 0);
            hb = __builtin_amdgcn_mfma_f32_32x32x16_bf16(afrag[ks + 1], bf1, hb, 0, 0, 0);
        }
        {   // bias + GELU -> hbuf
            float bb = b1[ch * 64 + 32 * g1n + l31];
            #pragma unroll
            for (int r = 0; r < 16; ++r) {
                int row = 32 * g1m + (r & 3) + 8 * (r >> 2) + 4 * half;
                float v = gelu_f(ha[r] + hb[r] + bb);
                hbuf[row * W2_STRIDE + 32 * g1n + l31] = f2bf(v);
            }
        }
        BAR_SYNC_LDS();                          // B1: hbuf visible; W1buf reads done
        if (ch < 15) {
            // write w1[ch+1] -> W1buf (drained by B2); prefetch w2[ch+1] (covered by GEMM2)
            #pragma unroll
            for (int j = 0; j < 8; ++j) wb1[j * 256 + t] = w1reg[j];
            if (t < 80) wb1[2048 + t] = w1reg[8];
            const u32x4* s2 = (const u32x4*)(w2p + (size_t)(ch + 1) * W2_CHUNK);
            #pragma unroll
            for (int j = 0; j < 9; ++j) w2reg[j] = s2[j * 256 + t];
            if (t < 64) w2reg[9] = s2[2304 + t];
        }
        // ---- GEMM2: out += H @ w2[ch]
        #pragma unroll
        for (int ks = 0; ks < 4; ++ks) {
            short8 haf = *(const short8*)(hbuf + (32 * g2m + l31) * W2_STRIDE + ks * 16 + half * 8);
            #pragma unroll
            for (int nt = 0; nt < 4; ++nt) {
                short8 bfr = *(const short8*)(w2b + (g2nb + 32 * nt + l31) * W2_STRIDE + ks * 16 + half * 8);
                oacc[nt] = __builtin_amdgcn_mfma_f32_32x32x16_bf16(haf, bfr, oacc[nt], 0, 0, 0);
            }
        }
        BAR_SYNC_LDS();                          // B2: W2buf + hbuf reads done; w1 writes drained
        if (ch < 15) {
            // write w2[ch+1] -> W2buf (drained by next B1)
            #pragma unroll
            for (int j = 0; j < 9; ++j) wb2[j * 256 + t] = w2reg[j];
            if (t < 64) wb2[2304 + t] = w2reg[9];
        }
    }

    // epilogue: + bm2 (residual folded in at the store loop)
    #pragma unroll
    for (int nt = 0; nt < 4; ++nt) {
        int col = g2nb + 32 * nt + l31;
        float bb = bm2[col];
        #pragma unroll
        for (int r = 0; r < 16; ++r)
            oacc[nt][r] += bb;
    }
    BAR_SYNC_LDS();   // last chunk's trailing ds ops done -> ot_s overlay safe
    #pragma unroll
    for (int nt = 0; nt < 4; ++nt) {
        int col = g2nb + 32 * nt + l31;
        #pragma unroll
        for (int r = 0; r < 16; ++r) {
            int row = 32 * g2m + (r & 3) + 8 * (r >> 2) + 4 * half;
            ot_s[col * W2_STRIDE + row] = f2bf(oacc[nt][r]);
        }
    }
    BAR_SYNC_LDS();
    {   // coalesced fp32 NCHW store; residual x2 = bf16(bf16(x)+bout) recomputed here
        for (int it = 0; it < 64; ++it) {
            int c = it * 4 + wv;
            float accv = bf2f(ot_s[c * W2_STRIDE + lane]);
            float xv   = x[(size_t)c * 65536 + p0 + lane];
            float bo   = bf2f(bout[(size_t)(p0 + lane) * 256 + c]);
            // same rounding chain as the old x2_s path (residual added in fp32)
            float x2v  = bf2f(f2bf(bf2f(f2bf(xv)) + bo));
            out[(size_t)c * 65536 + p0 + lane] = accv + x2v;
        }
    }
}

extern "C" void kernel_launch(void* const* d_in, const int* in_sizes, int n_in,
                              void* d_out, int out_size, void* d_ws, size_t ws_size,
                              hipStream_t stream) {
    (void)in_sizes; (void)n_in; (void)out_size; (void)ws_size;
    const float* x     = (const float*)d_in[0];
    const float* n1g   = (const float*)d_in[1];
    const float* n1b   = (const float*)d_in[2];
    const float* qkv_r = (const float*)d_in[3];
    const float* pr_w  = (const float*)d_in[4];
    const float* pr_b  = (const float*)d_in[5];
    const float* tab_r = (const float*)d_in[6];
    const float* qkv_a = (const float*)d_in[7];
    const float* pa_w  = (const float*)d_in[8];
    const float* pa_b  = (const float*)d_in[9];
    const float* tab_a = (const float*)d_in[10];
    const float* n2g   = (const float*)d_in[11];
    const float* n2b   = (const float*)d_in[12];
    const float* w1    = (const float*)d_in[13];
    const float* b1    = (const float*)d_in[14];
    const float* w2    = (const float*)d_in[15];
    const float* b2    = (const float*)d_in[16];

    char* ws = (char*)d_ws;
    ushort_t* wqkvT_r = (ushort_t*)(ws);              //  98304 B
    ushort_t* wqkvT_a = (ushort_t*)(ws + 98304);      //  98304 B
    ushort_t* wpT_r   = (ushort_t*)(ws + 196608);     //  32768 B
    ushort_t* wpT_a   = (ushort_t*)(ws + 229376);     //  32768 B
    ushort_t* w1p     = (ushort_t*)(ws + 262144);     // 544768 B  [16][64][266]
    ushort_t* w2p     = (ushort_t*)(ws + 806912);     // 606208 B  [16][256][74]
    ushort_t* bout    = (ushort_t*)(ws + 1413120);    // 33554432 B
    ushort_t* xn      = (ushort_t*)d_out;             // staged in d_out (dead before mlp_k)

    prep_k<<<1664, 256, 0, stream>>>(x, n1g, n1b, xn,
                                     qkv_r, wqkvT_r, qkv_a, wqkvT_a,
                                     pr_w, wpT_r, pa_w, wpT_a,
                                     w1, w1p, w2, w2p);
    attn_k<<<dim3(1024, 2), 256, 0, stream>>>(xn, wqkvT_r, wpT_r, pr_b, tab_r,
                                              wqkvT_a, wpT_a, pa_b, tab_a, bout);
    mlp_k<<<1024, 256, 0, stream>>>(x, bout, n2g, n2b, w1p, b1, w2p, b2, (float*)d_out);
}

// Round 4
// 623.459 us; speedup vs baseline: 1.0129x; 1.0129x over previous
//
#include <hip/hip_runtime.h>
#include <stdint.h>

typedef unsigned short ushort_t;
typedef __attribute__((ext_vector_type(8))) short short8;       // 8 x bf16 (MFMA A/B frag)
typedef __attribute__((ext_vector_type(4))) float floatx4;      // 16x16 C frag / 16B fp32
typedef __attribute__((ext_vector_type(16))) float floatx16;    // 32x32 C frag
typedef __attribute__((ext_vector_type(4))) unsigned int u32x4; // 16B vector

__device__ __forceinline__ float bf2f(ushort_t u) {
    union { unsigned int i; float f; } v; v.i = ((unsigned int)u) << 16; return v.f;
}
__device__ __forceinline__ ushort_t f2bf(float f) {
    union { float ff; unsigned int i; } v; v.ff = f;
    unsigned int x = v.i;
    return (ushort_t)((x + 0x7fffu + ((x >> 16) & 1u)) >> 16);  // RNE
}
// Packed RNE fp32x2 -> bf16x2 (lo = a, hi = b). Same rounding as f2bf.
__device__ __forceinline__ unsigned int f2bf2(float a, float b) {
    unsigned int r;
    asm("v_cvt_pk_bf16_f32 %0, %1, %2" : "=v"(r) : "v"(a), "v"(b));
    return r;
}
__device__ __forceinline__ float gelu_f(float v) {
    // 0.5v(1+tanh(u)) == v * sigmoid(2u)
    float u = v * (0.7978845608f + 0.0356774081f * v * v);
    return v * __fdividef(1.f, 1.f + __expf(-2.f * u));
}
#define LDS_ROUNDTRIP_FENCE() __asm__ volatile("s_waitcnt lgkmcnt(0)" ::: "memory")
// LDS-only barrier: orders ds ops across the workgroup WITHOUT draining vmcnt.
// Safe whenever cross-wave data flows through LDS only (validated R1/R3 runs).
#define BAR_SYNC_LDS() __asm__ volatile("s_waitcnt lgkmcnt(0)\n\ts_barrier" ::: "memory")

// Padded weight-prep strides (odd dword counts -> conflict-free ds_read_b128):
// w1p: [16][64][266] bf16 (133 dwords/row), w2p: [16][256][74] bf16 (37 dwords/row)
#define W1_STRIDE 266
#define W1_CHUNK  17024   // ushorts; 34048 B = 2128 u32x4 (8*256 + 80)
#define W2_STRIDE 74
#define W2_CHUNK  18944   // ushorts; 37888 B = 2368 u32x4 (9*256 + 64)

// ================= prep_k: ln1 (blocks 0..1023) + all weight preps (1024..1663) ==========
__global__ __launch_bounds__(256) void prep_k(
    const float* __restrict__ x, const float* __restrict__ n1g, const float* __restrict__ n1b,
    ushort_t* __restrict__ xn,
    const float* __restrict__ qkv_r, ushort_t* __restrict__ wqkvT_r,
    const float* __restrict__ qkv_a, ushort_t* __restrict__ wqkvT_a,
    const float* __restrict__ pr_w,  ushort_t* __restrict__ wpT_r,
    const float* __restrict__ pa_w,  ushort_t* __restrict__ wpT_a,
    const float* __restrict__ w1,    ushort_t* __restrict__ w1p,
    const float* __restrict__ w2,    ushort_t* __restrict__ w2p)
{
    __shared__ __align__(16) char pshm[33792];
    const int t = threadIdx.x;
    int b = blockIdx.x;
    if (b < 1024) {
        // ---- LN1 + NCHW(fp32) -> NHWC(bf16) ----
        ushort_t* tile = (ushort_t*)pshm;    // [64][264]
        const int p0 = b * 64;
        {
            const int pg = t & 15, cb = t >> 4;
            for (int it = 0; it < 16; ++it) {
                int c = cb + 16 * it;
                floatx4 v = *(const floatx4*)(x + (size_t)c * 65536 + p0 + pg * 4);
                unsigned int pk01 = f2bf2(v[0], v[1]);
                unsigned int pk23 = f2bf2(v[2], v[3]);
                tile[(pg * 4 + 0) * 264 + c] = (ushort_t)pk01;
                tile[(pg * 4 + 1) * 264 + c] = (ushort_t)(pk01 >> 16);
                tile[(pg * 4 + 2) * 264 + c] = (ushort_t)pk23;
                tile[(pg * 4 + 3) * 264 + c] = (ushort_t)(pk23 >> 16);
            }
        }
        __syncthreads();
        const int pix = t >> 2, part = t & 3;
        float vals[64];
        float s = 0.f, ss = 0.f;
        #pragma unroll
        for (int k = 0; k < 64; ++k) {
            float v = bf2f(tile[pix * 264 + part * 64 + k]);
            vals[k] = v; s += v; ss += v * v;
        }
        s  += __shfl_xor(s, 1);  s  += __shfl_xor(s, 2);
        ss += __shfl_xor(ss, 1); ss += __shfl_xor(ss, 2);
        float mean = s * (1.f / 256.f);
        float rstd = rsqrtf(ss * (1.f / 256.f) - mean * mean + 1e-5f);
        size_t obase = (size_t)(p0 + pix) * 256 + part * 64;
        #pragma unroll
        for (int k8 = 0; k8 < 8; ++k8) {
            alignas(16) unsigned int o4[4];
            #pragma unroll
            for (int kk = 0; kk < 4; ++kk) {
                int c = part * 64 + k8 * 8 + kk * 2;
                float f0 = (vals[k8 * 8 + kk * 2]     - mean) * rstd * n1g[c]     + n1b[c];
                float f1 = (vals[k8 * 8 + kk * 2 + 1] - mean) * rstd * n1g[c + 1] + n1b[c + 1];
                o4[kk] = f2bf2(f0, f1);
            }
            *(u32x4*)(xn + obase + k8 * 8) = *(const u32x4*)o4;
        }
        return;
    }
    b -= 1024;
    if (b < 512) {
        // ---- simple transposes fp32 [R][C] -> bf16 [C][R] ----
        const float* src; ushort_t* dst; int R, C, bi;
        if (b < 192)      { src = qkv_r; dst = wqkvT_r; R = 128; C = 384; bi = b;       }
        else if (b < 384) { src = qkv_a; dst = wqkvT_a; R = 128; C = 384; bi = b - 192; }
        else if (b < 448) { src = pr_w;  dst = wpT_r;   R = 128; C = 128; bi = b - 384; }
        else              { src = pa_w;  dst = wpT_a;   R = 128; C = 128; bi = b - 448; }
        int nbx = C / 16;
        int c0 = (bi % nbx) * 16, r0 = (bi / nbx) * 16;
        float* ts = (float*)pshm;    // [16][17]
        int tx = t & 15, ty = t >> 4;
        ts[ty * 17 + tx] = src[(size_t)(r0 + ty) * C + (c0 + tx)];
        __syncthreads();
        dst[(size_t)(c0 + ty) * R + (r0 + tx)] = f2bf(ts[tx * 17 + ty]);
        return;
    }
    b -= 512;
    float* s = (float*)pshm;   // [64][65]
    if (b < 64) {
        // ---- w1prep: w1 fp32 [256][1024] -> [16][64][266] (padded) ----
        const int ch = b & 15, k0 = (b >> 4) * 64;
        {
            int nn = t & 63, kr = t >> 6;
            for (int j = 0; j < 16; ++j) {
                int kk = j * 4 + kr;
                s[kk * 65 + nn] = w1[(size_t)(k0 + kk) * 1024 + ch * 64 + nn];
            }
        }
        __syncthreads();
        {
            int kk = t & 63, nr = t >> 6;
            for (int j = 0; j < 16; ++j) {
                int n2 = j * 4 + nr;
                w1p[(size_t)ch * W1_CHUNK + n2 * W1_STRIDE + k0 + kk] = f2bf(s[kk * 65 + n2]);
            }
        }
        return;
    }
    b -= 64;
    {
        // ---- w2prep: w2 fp32 [1024][256] -> [16][256][74] (padded) ----
        const int ch = b & 15, n0 = (b >> 4) * 64;
        {
            int nn = t & 63, kr = t >> 6;
            for (int j = 0; j < 16; ++j) {
                int kk = j * 4 + kr;
                s[kk * 65 + nn] = w2[(size_t)(ch * 64 + kk) * 256 + n0 + nn];
            }
        }
        __syncthreads();
        {
            int kk = t & 63, nr = t >> 6;
            for (int j = 0; j < 16; ++j) {
                int n2 = j * 4 + nr;
                w2p[(size_t)ch * W2_CHUNK + (n0 + n2) * W2_STRIDE + kk] = f2bf(s[kk * 65 + n2]);
            }
        }
    }
}

// ================= attn_k: one window per block (unchanged, proven) =================
__global__ __launch_bounds__(256, 2) void attn_k(
    const ushort_t* __restrict__ xn,
    const ushort_t* __restrict__ wqkvT_r, const ushort_t* __restrict__ wpT_r,
    const float* __restrict__ bp_r, const float* __restrict__ table_r,
    const ushort_t* __restrict__ wqkvT_a, const ushort_t* __restrict__ wpT_a,
    const float* __restrict__ bp_a, const float* __restrict__ table_a,
    ushort_t* __restrict__ bout)
{
    __shared__ __align__(16) char smem_raw[71680];
    ushort_t* xw_s = (ushort_t*)smem_raw;                   // [64][136]
    ushort_t* q_s  = (ushort_t*)(smem_raw + 17408);         // q [64][136] / P [2][64][72]
    ushort_t* k_s  = (ushort_t*)(smem_raw + 35840);         // k [64][136] / O [64][136]
    ushort_t* v_s  = (ushort_t*)(smem_raw + 53248);         // vT [128][72]

    const int br  = blockIdx.y;
    const int wid = blockIdx.x;
    const int t = threadIdx.x;
    const int wv = t >> 6, lane = t & 63, l15 = lane & 15, quad = lane >> 4;

    const int WwLog = br ? 4 : 2;
    const int WhLog = br ? 2 : 4;
    const int nWxLog = 8 - WwLog;
    const int wx = wid & ((1 << nWxLog) - 1);
    const int wy = wid >> nWxLog;
    const int chOff = br ? 128 : 0;
    const int WwM1 = (1 << WwLog) - 1, WhM1 = (1 << WhLog) - 1;
    const int biasMul = 2 * (1 << WwLog) - 1;
    const ushort_t* wqkvT = br ? wqkvT_a : wqkvT_r;
    const ushort_t* wpT   = br ? wpT_a   : wpT_r;
    const float* bp    = br ? bp_a    : bp_r;
    const float* table = br ? table_a : table_r;

    auto tok2p = [&](int n) -> int {
        int i = n >> WwLog, j = n & WwM1;
        return ((wy << WhLog) + i) * 256 + (wx << WwLog) + j;
    };

    {
        int tok = t >> 2, seg = t & 3;
        const ushort_t* src = xn + (size_t)tok2p(tok) * 256 + chOff + seg * 32;
        ushort_t* dst = xw_s + tok * 136 + seg * 32;
        *(u32x4*)(dst)      = *(const u32x4*)(src);
        *(u32x4*)(dst + 8)  = *(const u32x4*)(src + 8);
        *(u32x4*)(dst + 16) = *(const u32x4*)(src + 16);
        *(u32x4*)(dst + 24) = *(const u32x4*)(src + 24);
    }
    __syncthreads();

    {
        short8 afrag[4];
        #pragma unroll
        for (int kt = 0; kt < 4; ++kt)
            afrag[kt] = *(const short8*)(xw_s + (16 * wv + l15) * 136 + kt * 32 + quad * 8);
        for (int nt = 0; nt < 24; ++nt) {
            floatx4 acc = {0.f, 0.f, 0.f, 0.f};
            const ushort_t* wb = wqkvT + (size_t)(nt * 16 + l15) * 128 + quad * 8;
            #pragma unroll
            for (int kt = 0; kt < 4; ++kt)
                acc = __builtin_amdgcn_mfma_f32_16x16x32_bf16(afrag[kt],
                        *(const short8*)(wb + kt * 32), acc, 0, 0, 0);
            int ncol = nt * 16 + l15;
            #pragma unroll
            for (int r = 0; r < 4; ++r) {
                int row = 16 * wv + quad * 4 + r;
                ushort_t val = f2bf(acc[r]);
                if (ncol < 128)      q_s[row * 136 + ncol] = val;
                else if (ncol < 256) k_s[row * 136 + (ncol - 128)] = val;
                else                 v_s[(ncol - 256) * 72 + row] = val;
            }
        }
    }
    __syncthreads();

    float pvals[2][4][4];
    #pragma unroll
    for (int head = 0; head < 2; ++head) {
        floatx4 sacc[4];
        #pragma unroll
        for (int nt = 0; nt < 4; ++nt) sacc[nt] = floatx4{0.f, 0.f, 0.f, 0.f};
        #pragma unroll
        for (int kt = 0; kt < 2; ++kt) {
            short8 aq = *(const short8*)(q_s + (16 * wv + l15) * 136 + head * 64 + kt * 32 + quad * 8);
            #pragma unroll
            for (int nt = 0; nt < 4; ++nt) {
                short8 bk = *(const short8*)(k_s + (nt * 16 + l15) * 136 + head * 64 + kt * 32 + quad * 8);
                sacc[nt] = __builtin_amdgcn_mfma_f32_16x16x32_bf16(aq, bk, sacc[nt], 0, 0, 0);
            }
        }
        #pragma unroll
        for (int r = 0; r < 4; ++r) {
            int qrow = 16 * wv + quad * 4 + r;
            int iq = qrow >> WwLog, jq = qrow & WwM1;
            float v[4], mx = -1e30f;
            #pragma unroll
            for (int nt = 0; nt < 4; ++nt) {
                int kcol = nt * 16 + l15;
                int ik = kcol >> WwLog, jk = kcol & WwM1;
                int idx = (iq - ik + WhM1) * biasMul + (jq - jk + WwM1);
                v[nt] = sacc[nt][r] * 0.125f + table[idx * 2 + head];
                mx = fmaxf(mx, v[nt]);
            }
            mx = fmaxf(mx, __shfl_xor(mx, 1)); mx = fmaxf(mx, __shfl_xor(mx, 2));
            mx = fmaxf(mx, __shfl_xor(mx, 4)); mx = fmaxf(mx, __shfl_xor(mx, 8));
            float e[4], sm = 0.f;
            #pragma unroll
            for (int nt = 0; nt < 4; ++nt) { e[nt] = __expf(v[nt] - mx); sm += e[nt]; }
            sm += __shfl_xor(sm, 1); sm += __shfl_xor(sm, 2);
            sm += __shfl_xor(sm, 4); sm += __shfl_xor(sm, 8);
            float inv = 1.f / sm;
            #pragma unroll
            for (int nt = 0; nt < 4; ++nt) pvals[head][nt][r] = e[nt] * inv;
        }
    }
    __syncthreads();

    {
        ushort_t* p_s = q_s;
        #pragma unroll
        for (int head = 0; head < 2; ++head)
            #pragma unroll
            for (int nt = 0; nt < 4; ++nt)
                #pragma unroll
                for (int r = 0; r < 4; ++r) {
                    int row = 16 * wv + quad * 4 + r;
                    p_s[(head * 64 + row) * 72 + nt * 16 + l15] = f2bf(pvals[head][nt][r]);
                }
    }
    LDS_ROUNDTRIP_FENCE();
    {
        const ushort_t* p_s = q_s;
        ushort_t* o_s = k_s;
        #pragma unroll
        for (int head = 0; head < 2; ++head) {
            short8 ap[2];
            #pragma unroll
            for (int kt = 0; kt < 2; ++kt)
                ap[kt] = *(const short8*)(p_s + (head * 64 + 16 * wv + l15) * 72 + kt * 32 + quad * 8);
            #pragma unroll
            for (int nt = 0; nt < 4; ++nt) {
                floatx4 acc = {0.f, 0.f, 0.f, 0.f};
                #pragma unroll
                for (int kt = 0; kt < 2; ++kt) {
                    short8 bv = *(const short8*)(v_s + (head * 64 + nt * 16 + l15) * 72 + kt * 32 + quad * 8);
                    acc = __builtin_amdgcn_mfma_f32_16x16x32_bf16(ap[kt], bv, acc, 0, 0, 0);
                }
                #pragma unroll
                for (int r = 0; r < 4; ++r)
                    o_s[(16 * wv + quad * 4 + r) * 136 + head * 64 + nt * 16 + l15] = f2bf(acc[r]);
            }
        }
    }
    __syncthreads();

    {
        const ushort_t* o_s = k_s;
        short8 ao[4];
        #pragma unroll
        for (int kt = 0; kt < 4; ++kt)
            ao[kt] = *(const short8*)(o_s + (16 * wv + l15) * 136 + kt * 32 + quad * 8);
        #pragma unroll
        for (int nt = 0; nt < 8; ++nt) {
            floatx4 acc = {0.f, 0.f, 0.f, 0.f};
            const ushort_t* wb = wpT + (size_t)(nt * 16 + l15) * 128 + quad * 8;
            #pragma unroll
            for (int kt = 0; kt < 4; ++kt)
                acc = __builtin_amdgcn_mfma_f32_16x16x32_bf16(ao[kt],
                        *(const short8*)(wb + kt * 32), acc, 0, 0, 0);
            int col = nt * 16 + l15;
            float bpv = bp[col];
            #pragma unroll
            for (int r = 0; r < 4; ++r) {
                int row = 16 * wv + quad * 4 + r;
                float res = acc[r] + bpv + bf2f(xw_s[row * 136 + col]);
                bout[(size_t)tok2p(row) * 256 + chOff + col] = f2bf(res);
            }
        }
    }
}

// ================= mlp_k v8: v4 structure + padded strides + packed cvt + lgkm barriers ===
// LDS 81152 B (2 blocks/CU):
//   x2_s [64][264] @0      (33792, live to epilogue)
//   wbuf @33792            (37888: xn_s [64][264] transient -> w1 [64][266] / w2 [256][74])
//   hbuf [64][74]  @71680  (9472)
//   ot_s [256][74] @0      (37888, epilogue overlay)
__global__ __launch_bounds__(256, 2) void mlp_k(
    const float* __restrict__ x,          // NCHW fp32
    const ushort_t* __restrict__ bout,    // NHWC bf16
    const float* __restrict__ g2, const float* __restrict__ b2,
    const ushort_t* __restrict__ w1p, const float* __restrict__ b1,
    const ushort_t* __restrict__ w2p, const float* __restrict__ bm2,
    float* __restrict__ out)
{
    __shared__ __align__(16) char smem_raw[81152];
    ushort_t* x2_s = (ushort_t*)smem_raw;               // [64][264]
    ushort_t* wbuf = (ushort_t*)(smem_raw + 33792);     // union xn_s / w1 / w2 chunk
    ushort_t* hbuf = (ushort_t*)(smem_raw + 71680);     // [64][74]
    ushort_t* xn_s = wbuf;                              // [64][264] transient overlay
    ushort_t* ot_s = (ushort_t*)smem_raw;               // [256][74] epilogue overlay

    const int t = threadIdx.x;
    const int p0 = blockIdx.x * 64;
    const int wv = t >> 6, lane = t & 63, l31 = lane & 31, half = lane >> 5;

    {   // x fp32 NCHW tile -> x2_s bf16
        const int pg = t & 15, cb = t >> 4;
        for (int it = 0; it < 16; ++it) {
            int c = cb + 16 * it;
            floatx4 v = *(const floatx4*)(x + (size_t)c * 65536 + p0 + pg * 4);
            unsigned int pk01 = f2bf2(v[0], v[1]);
            unsigned int pk23 = f2bf2(v[2], v[3]);
            x2_s[(pg * 4 + 0) * 264 + c] = (ushort_t)pk01;
            x2_s[(pg * 4 + 1) * 264 + c] = (ushort_t)(pk01 >> 16);
            x2_s[(pg * 4 + 2) * 264 + c] = (ushort_t)pk23;
            x2_s[(pg * 4 + 3) * 264 + c] = (ushort_t)(pk23 >> 16);
        }
    }
    BAR_SYNC_LDS();
    {   // x2 = x + bout; LN2 -> xn_s
        const int row = t >> 2, part = t & 3;
        float vals[64];
        float s = 0.f, ss = 0.f;
        const ushort_t* bpr = bout + (size_t)(p0 + row) * 256 + part * 64;
        ushort_t* xpr = x2_s + row * 264 + part * 64;
        #pragma unroll
        for (int k8 = 0; k8 < 8; ++k8) {
            u32x4 bv = *(const u32x4*)(bpr + k8 * 8);
            u32x4 xv = *(const u32x4*)(xpr + k8 * 8);
            const ushort_t* pb = (const ushort_t*)&bv;
            const ushort_t* px = (const ushort_t*)&xv;
            #pragma unroll
            for (int k = 0; k < 8; ++k) {
                float v = bf2f(px[k]) + bf2f(pb[k]);
                vals[k8 * 8 + k] = v; s += v; ss += v * v;
            }
        }
        s  += __shfl_xor(s, 1);  s  += __shfl_xor(s, 2);
        ss += __shfl_xor(ss, 1); ss += __shfl_xor(ss, 2);
        float mean = s * (1.f / 256.f);
        float rstd = rsqrtf(ss * (1.f / 256.f) - mean * mean + 1e-5f);
        const float* g2p = g2 + part * 64;
        const float* b2p = b2 + part * 64;
        ushort_t* npr = xn_s + row * 264 + part * 64;
        #pragma unroll
        for (int k8 = 0; k8 < 8; ++k8) {
            alignas(16) unsigned int o4[4], n4[4];
            #pragma unroll
            for (int kk = 0; kk < 4; ++kk) {
                float v0 = vals[k8 * 8 + kk * 2];
                float v1 = vals[k8 * 8 + kk * 2 + 1];
                o4[kk] = f2bf2(v0, v1);
                int cc = k8 * 8 + kk * 2;
                n4[kk] = f2bf2((v0 - mean) * rstd * g2p[cc]     + b2p[cc],
                               (v1 - mean) * rstd * g2p[cc + 1] + b2p[cc + 1]);
            }
            *(u32x4*)(xpr + k8 * 8) = *(const u32x4*)o4;
            *(u32x4*)(npr + k8 * 8) = *(const u32x4*)n4;
        }
    }
    BAR_SYNC_LDS();

    // GEMM1 wave tile: rows 32*g1m..+31, hidden cols 32*g1n..+31 of the 64-col chunk
    const int g1m = wv & 1, g1n = wv >> 1;
    // GEMM2 wave tiles: rows 32*g2m..+31, out cols g2nb + {0,32,64,96}
    const int g2m = wv & 1;
    const int g2nb = 128 * (wv >> 1);

    short8 afrag[16];    // xn rows (32) x K=256, register-resident
    #pragma unroll
    for (int ks = 0; ks < 16; ++ks)
        afrag[ks] = *(const short8*)(xn_s + (32 * g1m + l31) * 264 + ks * 16 + half * 8);

    u32x4* wb16 = (u32x4*)wbuf;
    u32x4 w1reg[9], w2reg[10];
    {   // w1[0] chunk: 34048 B = 2128 u32x4 = 8*256 + 80
        const u32x4* s1 = (const u32x4*)w1p;
        #pragma unroll
        for (int j = 0; j < 8; ++j) w1reg[j] = s1[j * 256 + t];
        if (t < 80) w1reg[8] = s1[2048 + t];
    }
    BAR_SYNC_LDS();   // all afrag reads done (xn_s dead)
    {
        #pragma unroll
        for (int j = 0; j < 8; ++j) wb16[j * 256 + t] = w1reg[j];
        if (t < 80) wb16[2048 + t] = w1reg[8];
    }
    BAR_SYNC_LDS();   // wbuf = w1[0]

    floatx16 oacc[4];
    #pragma unroll
    for (int nt = 0; nt < 4; ++nt)
        #pragma unroll
        for (int i = 0; i < 16; ++i) oacc[nt][i] = 0.f;

    for (int ch = 0; ch < 16; ++ch) {
        {   // prefetch w2[ch] into regs (covered by GEMM1): 37888 B = 2368 u32x4 = 9*256 + 64
            const u32x4* s2 = (const u32x4*)(w2p + (size_t)ch * W2_CHUNK);
            #pragma unroll
            for (int j = 0; j < 9; ++j) w2reg[j] = s2[j * 256 + t];
            if (t < 64) w2reg[9] = s2[2304 + t];
        }
        // ---- GEMM1: H-chunk = xn @ w1[ch], two interleaved accumulator chains
        floatx16 ha, hb;
        #pragma unroll
        for (int i = 0; i < 16; ++i) { ha[i] = 0.f; hb[i] = 0.f; }
        #pragma unroll
        for (int ks = 0; ks < 16; ks += 2) {
            short8 bf0 = *(const short8*)(wbuf + (32 * g1n + l31) * W1_STRIDE + ks * 16 + half * 8);
            short8 bf1 = *(const short8*)(wbuf + (32 * g1n + l31) * W1_STRIDE + ks * 16 + 16 + half * 8);
            ha = __builtin_amdgcn_mfma_f32_32x32x16_bf16(afrag[ks], bf0, ha, 0, 0, 0);
            hb = __builtin_amdgcn_mfma_f32_32x32x16_bf16(afrag[ks + 1], bf1, hb, 0, 0, 0);
        }
        {   // bias + GELU -> hbuf (packed converts, scalar b16 stores)
            float bb = b1[ch * 64 + 32 * g1n + l31];
            int col = 32 * g1n + l31;
            #pragma unroll
            for (int r = 0; r < 16; r += 2) {
                float v0 = gelu_f(ha[r] + hb[r] + bb);
                float v1 = gelu_f(ha[r + 1] + hb[r + 1] + bb);
                unsigned int pk = f2bf2(v0, v1);
                int row0 = 32 * g1m + (r & 3) + 8 * (r >> 2) + 4 * half;
                hbuf[row0 * W2_STRIDE + col]       = (ushort_t)pk;
                hbuf[(row0 + 1) * W2_STRIDE + col] = (ushort_t)(pk >> 16);
            }
        }
        BAR_SYNC_LDS();                          // B1: w1 reads + hbuf writes done
        {
            #pragma unroll
            for (int j = 0; j < 9; ++j) wb16[j * 256 + t] = w2reg[j];
            if (t < 64) wb16[2304 + t] = w2reg[9];
        }
        BAR_SYNC_LDS();                          // B2: wbuf = w2[ch]
        if (ch < 15) {   // prefetch w1[ch+1] (covered by GEMM2)
            const u32x4* s1 = (const u32x4*)(w1p + (size_t)(ch + 1) * W1_CHUNK);
            #pragma unroll
            for (int j = 0; j < 8; ++j) w1reg[j] = s1[j * 256 + t];
            if (t < 80) w1reg[8] = s1[2048 + t];
        }
        // ---- GEMM2: out += H @ w2[ch]
        #pragma unroll
        for (int ks = 0; ks < 4; ++ks) {
            short8 haf = *(const short8*)(hbuf + (32 * g2m + l31) * W2_STRIDE + ks * 16 + half * 8);
            #pragma unroll
            for (int nt = 0; nt < 4; ++nt) {
                short8 bfr = *(const short8*)(wbuf + (g2nb + 32 * nt + l31) * W2_STRIDE + ks * 16 + half * 8);
                oacc[nt] = __builtin_amdgcn_mfma_f32_32x32x16_bf16(haf, bfr, oacc[nt], 0, 0, 0);
            }
        }
        BAR_SYNC_LDS();                          // B3: w2 + hbuf reads done
        if (ch < 15) {
            #pragma unroll
            for (int j = 0; j < 8; ++j) wb16[j * 256 + t] = w1reg[j];
            if (t < 80) wb16[2048 + t] = w1reg[8];
        }
        BAR_SYNC_LDS();                          // B4: wbuf = w1[ch+1]
    }

    // epilogue: + bm2 + x2 residual (x2_s still resident)
    #pragma unroll
    for (int nt = 0; nt < 4; ++nt) {
        int col = g2nb + 32 * nt + l31;
        float bb = bm2[col];
        #pragma unroll
        for (int r = 0; r < 16; ++r) {
            int row = 32 * g2m + (r & 3) + 8 * (r >> 2) + 4 * half;
            oacc[nt][r] += bb + bf2f(x2_s[row * 264 + col]);
        }
    }
    BAR_SYNC_LDS();   // x2_s/wbuf dead -> ot_s overlay safe
    #pragma unroll
    for (int nt = 0; nt < 4; ++nt) {
        int col = g2nb + 32 * nt + l31;
        #pragma unroll
        for (int r = 0; r < 16; r += 2) {
            int row0 = 32 * g2m + (r & 3) + 8 * (r >> 2) + 4 * half;   // even
            *(unsigned int*)(ot_s + col * W2_STRIDE + row0) = f2bf2(oacc[nt][r], oacc[nt][r + 1]);
        }
    }
    BAR_SYNC_LDS();
    {   // coalesced fp32 NCHW store: pixel-per-lane, channel per iteration
        for (int it = 0; it < 64; ++it) {
            int c = it * 4 + wv;
            out[(size_t)c * 65536 + p0 + lane] = bf2f(ot_s[c * W2_STRIDE + lane]);
        }
    }
}

extern "C" void kernel_launch(void* const* d_in, const int* in_sizes, int n_in,
                              void* d_out, int out_size, void* d_ws, size_t ws_size,
                              hipStream_t stream) {
    (void)in_sizes; (void)n_in; (void)out_size; (void)ws_size;
    const float* x     = (const float*)d_in[0];
    const float* n1g   = (const float*)d_in[1];
    const float* n1b   = (const float*)d_in[2];
    const float* qkv_r = (const float*)d_in[3];
    const float* pr_w  = (const float*)d_in[4];
    const float* pr_b  = (const float*)d_in[5];
    const float* tab_r = (const float*)d_in[6];
    const float* qkv_a = (const float*)d_in[7];
    const float* pa_w  = (const float*)d_in[8];
    const float* pa_b  = (const float*)d_in[9];
    const float* tab_a = (const float*)d_in[10];
    const float* n2g   = (const float*)d_in[11];
    const float* n2b   = (const float*)d_in[12];
    const float* w1    = (const float*)d_in[13];
    const float* b1    = (const float*)d_in[14];
    const float* w2    = (const float*)d_in[15];
    const float* b2    = (const float*)d_in[16];

    char* ws = (char*)d_ws;
    ushort_t* wqkvT_r = (ushort_t*)(ws);              //  98304 B
    ushort_t* wqkvT_a = (ushort_t*)(ws + 98304);      //  98304 B
    ushort_t* wpT_r   = (ushort_t*)(ws + 196608);     //  32768 B
    ushort_t* wpT_a   = (ushort_t*)(ws + 229376);     //  32768 B
    ushort_t* w1p     = (ushort_t*)(ws + 262144);     // 544768 B  [16][64][266]
    ushort_t* w2p     = (ushort_t*)(ws + 806912);     // 606208 B  [16][256][74]
    ushort_t* bout    = (ushort_t*)(ws + 1413120);    // 33554432 B
    ushort_t* xn      = (ushort_t*)d_out;             // staged in d_out (dead before mlp_k)

    prep_k<<<1664, 256, 0, stream>>>(x, n1g, n1b, xn,
                                     qkv_r, wqkvT_r, qkv_a, wqkvT_a,
                                     pr_w, wpT_r, pa_w, wpT_a,
                                     w1, w1p, w2, w2p);
    attn_k<<<dim3(1024, 2), 256, 0, stream>>>(xn, wqkvT_r, wpT_r, pr_b, tab_r,
                                              wqkvT_a, wpT_a, pa_b, tab_a, bout);
    mlp_k<<<1024, 256, 0, stream>>>(x, bout, n2g, n2b, w1p, b1, w2p, b2, (float*)d_out);
}

// Round 5
// 425.177 us; speedup vs baseline: 1.4853x; 1.4664x over previous
//
#include <hip/hip_runtime.h>
#include <stdint.h>

typedef unsigned short ushort_t;
typedef __attribute__((ext_vector_type(8))) short short8;       // 8 x bf16 (MFMA A/B frag)
typedef __attribute__((ext_vector_type(4))) float floatx4;      // 16x16 C frag / 16B fp32
typedef __attribute__((ext_vector_type(16))) float floatx16;    // 32x32 C frag
typedef __attribute__((ext_vector_type(4))) unsigned int u32x4; // 16B vector

__device__ __forceinline__ float bf2f(ushort_t u) {
    union { unsigned int i; float f; } v; v.i = ((unsigned int)u) << 16; return v.f;
}
__device__ __forceinline__ ushort_t f2bf(float f) {
    union { float ff; unsigned int i; } v; v.ff = f;
    unsigned int x = v.i;
    return (ushort_t)((x + 0x7fffu + ((x >> 16) & 1u)) >> 16);  // RNE
}
// Packed RNE fp32x2 -> bf16x2 (lo = a, hi = b). Same rounding as f2bf (verified R4 run).
__device__ __forceinline__ unsigned int f2bf2(float a, float b) {
    unsigned int r;
    asm("v_cvt_pk_bf16_f32 %0, %1, %2" : "=v"(r) : "v"(a), "v"(b));
    return r;
}
__device__ __forceinline__ float gelu_f(float v) {
    // 0.5v(1+tanh(u)) == v * sigmoid(2u)  (verified within harness tolerance, R4 run)
    float u = v * (0.7978845608f + 0.0356774081f * v * v);
    return v * __fdividef(1.f, 1.f + __expf(-2.f * u));
}
#define LDS_ROUNDTRIP_FENCE() __asm__ volatile("s_waitcnt lgkmcnt(0)" ::: "memory")
// NOTE (journal): the asm "s_waitcnt lgkmcnt(0); s_barrier" macro used in v7/v8 correlates
// with a 2.2x mlp_k slowdown vs plain __syncthreads() at identical structure (166 -> 365us,
// pure stall: MFMA/VALU time unchanged). Reverted to __syncthreads() everywhere in mlp_k.

// ================= prep_k: ln1 (blocks 0..1023) + all weight preps (1024..1663) ==========
__global__ __launch_bounds__(256) void prep_k(
    const float* __restrict__ x, const float* __restrict__ n1g, const float* __restrict__ n1b,
    ushort_t* __restrict__ xn,
    const float* __restrict__ qkv_r, ushort_t* __restrict__ wqkvT_r,
    const float* __restrict__ qkv_a, ushort_t* __restrict__ wqkvT_a,
    const float* __restrict__ pr_w,  ushort_t* __restrict__ wpT_r,
    const float* __restrict__ pa_w,  ushort_t* __restrict__ wpT_a,
    const float* __restrict__ w1,    ushort_t* __restrict__ w1p,
    const float* __restrict__ w2,    ushort_t* __restrict__ w2p)
{
    __shared__ __align__(16) char pshm[33792];
    const int t = threadIdx.x;
    int b = blockIdx.x;
    if (b < 1024) {
        // ---- LN1 + NCHW(fp32) -> NHWC(bf16) ----
        ushort_t* tile = (ushort_t*)pshm;    // [64][264]
        const int p0 = b * 64;
        {
            const int pg = t & 15, cb = t >> 4;
            for (int it = 0; it < 16; ++it) {
                int c = cb + 16 * it;
                floatx4 v = *(const floatx4*)(x + (size_t)c * 65536 + p0 + pg * 4);
                unsigned int pk01 = f2bf2(v[0], v[1]);
                unsigned int pk23 = f2bf2(v[2], v[3]);
                tile[(pg * 4 + 0) * 264 + c] = (ushort_t)pk01;
                tile[(pg * 4 + 1) * 264 + c] = (ushort_t)(pk01 >> 16);
                tile[(pg * 4 + 2) * 264 + c] = (ushort_t)pk23;
                tile[(pg * 4 + 3) * 264 + c] = (ushort_t)(pk23 >> 16);
            }
        }
        __syncthreads();
        const int pix = t >> 2, part = t & 3;
        float vals[64];
        float s = 0.f, ss = 0.f;
        #pragma unroll
        for (int k = 0; k < 64; ++k) {
            float v = bf2f(tile[pix * 264 + part * 64 + k]);
            vals[k] = v; s += v; ss += v * v;
        }
        s  += __shfl_xor(s, 1);  s  += __shfl_xor(s, 2);
        ss += __shfl_xor(ss, 1); ss += __shfl_xor(ss, 2);
        float mean = s * (1.f / 256.f);
        float rstd = rsqrtf(ss * (1.f / 256.f) - mean * mean + 1e-5f);
        size_t obase = (size_t)(p0 + pix) * 256 + part * 64;
        #pragma unroll
        for (int k8 = 0; k8 < 8; ++k8) {
            alignas(16) unsigned int o4[4];
            #pragma unroll
            for (int kk = 0; kk < 4; ++kk) {
                int c = part * 64 + k8 * 8 + kk * 2;
                float f0 = (vals[k8 * 8 + kk * 2]     - mean) * rstd * n1g[c]     + n1b[c];
                float f1 = (vals[k8 * 8 + kk * 2 + 1] - mean) * rstd * n1g[c + 1] + n1b[c + 1];
                o4[kk] = f2bf2(f0, f1);
            }
            *(u32x4*)(xn + obase + k8 * 8) = *(const u32x4*)o4;
        }
        return;
    }
    b -= 1024;
    if (b < 512) {
        // ---- simple transposes fp32 [R][C] -> bf16 [C][R] ----
        const float* src; ushort_t* dst; int R, C, bi;
        if (b < 192)      { src = qkv_r; dst = wqkvT_r; R = 128; C = 384; bi = b;       }
        else if (b < 384) { src = qkv_a; dst = wqkvT_a; R = 128; C = 384; bi = b - 192; }
        else if (b < 448) { src = pr_w;  dst = wpT_r;   R = 128; C = 128; bi = b - 384; }
        else              { src = pa_w;  dst = wpT_a;   R = 128; C = 128; bi = b - 448; }
        int nbx = C / 16;
        int c0 = (bi % nbx) * 16, r0 = (bi / nbx) * 16;
        float* ts = (float*)pshm;    // [16][17]
        int tx = t & 15, ty = t >> 4;
        ts[ty * 17 + tx] = src[(size_t)(r0 + ty) * C + (c0 + tx)];
        __syncthreads();
        dst[(size_t)(c0 + ty) * R + (r0 + tx)] = f2bf(ts[tx * 17 + ty]);
        return;
    }
    b -= 512;
    float* s = (float*)pshm;   // [64][65]
    if (b < 64) {
        // ---- w1prep: w1 fp32 [256][1024] -> [16][64][264] ----
        const int ch = b & 15, k0 = (b >> 4) * 64;
        {
            int nn = t & 63, kr = t >> 6;
            for (int j = 0; j < 16; ++j) {
                int kk = j * 4 + kr;
                s[kk * 65 + nn] = w1[(size_t)(k0 + kk) * 1024 + ch * 64 + nn];
            }
        }
        __syncthreads();
        {
            int kk = t & 63, nr = t >> 6;
            for (int j = 0; j < 16; ++j) {
                int n2 = j * 4 + nr;
                w1p[(size_t)ch * 16896 + n2 * 264 + k0 + kk] = f2bf(s[kk * 65 + n2]);
            }
        }
        return;
    }
    b -= 64;
    {
        // ---- w2prep: w2 fp32 [1024][256] -> [16][256][72] ----
        const int ch = b & 15, n0 = (b >> 4) * 64;
        {
            int nn = t & 63, kr = t >> 6;
            for (int j = 0; j < 16; ++j) {
                int kk = j * 4 + kr;
                s[kk * 65 + nn] = w2[(size_t)(ch * 64 + kk) * 256 + n0 + nn];
            }
        }
        __syncthreads();
        {
            int kk = t & 63, nr = t >> 6;
            for (int j = 0; j < 16; ++j) {
                int n2 = j * 4 + nr;
                w2p[(size_t)ch * 18432 + (n0 + n2) * 72 + kk] = f2bf(s[kk * 65 + n2]);
            }
        }
    }
}

// ================= attn_k: one window per block (unchanged, proven) =================
__global__ __launch_bounds__(256, 2) void attn_k(
    const ushort_t* __restrict__ xn,
    const ushort_t* __restrict__ wqkvT_r, const ushort_t* __restrict__ wpT_r,
    const float* __restrict__ bp_r, const float* __restrict__ table_r,
    const ushort_t* __restrict__ wqkvT_a, const ushort_t* __restrict__ wpT_a,
    const float* __restrict__ bp_a, const float* __restrict__ table_a,
    ushort_t* __restrict__ bout)
{
    __shared__ __align__(16) char smem_raw[71680];
    ushort_t* xw_s = (ushort_t*)smem_raw;                   // [64][136]
    ushort_t* q_s  = (ushort_t*)(smem_raw + 17408);         // q [64][136] / P [2][64][72]
    ushort_t* k_s  = (ushort_t*)(smem_raw + 35840);         // k [64][136] / O [64][136]
    ushort_t* v_s  = (ushort_t*)(smem_raw + 53248);         // vT [128][72]

    const int br  = blockIdx.y;
    const int wid = blockIdx.x;
    const int t = threadIdx.x;
    const int wv = t >> 6, lane = t & 63, l15 = lane & 15, quad = lane >> 4;

    const int WwLog = br ? 4 : 2;
    const int WhLog = br ? 2 : 4;
    const int nWxLog = 8 - WwLog;
    const int wx = wid & ((1 << nWxLog) - 1);
    const int wy = wid >> nWxLog;
    const int chOff = br ? 128 : 0;
    const int WwM1 = (1 << WwLog) - 1, WhM1 = (1 << WhLog) - 1;
    const int biasMul = 2 * (1 << WwLog) - 1;
    const ushort_t* wqkvT = br ? wqkvT_a : wqkvT_r;
    const ushort_t* wpT   = br ? wpT_a   : wpT_r;
    const float* bp    = br ? bp_a    : bp_r;
    const float* table = br ? table_a : table_r;

    auto tok2p = [&](int n) -> int {
        int i = n >> WwLog, j = n & WwM1;
        return ((wy << WhLog) + i) * 256 + (wx << WwLog) + j;
    };

    {
        int tok = t >> 2, seg = t & 3;
        const ushort_t* src = xn + (size_t)tok2p(tok) * 256 + chOff + seg * 32;
        ushort_t* dst = xw_s + tok * 136 + seg * 32;
        *(u32x4*)(dst)      = *(const u32x4*)(src);
        *(u32x4*)(dst + 8)  = *(const u32x4*)(src + 8);
        *(u32x4*)(dst + 16) = *(const u32x4*)(src + 16);
        *(u32x4*)(dst + 24) = *(const u32x4*)(src + 24);
    }
    __syncthreads();

    {
        short8 afrag[4];
        #pragma unroll
        for (int kt = 0; kt < 4; ++kt)
            afrag[kt] = *(const short8*)(xw_s + (16 * wv + l15) * 136 + kt * 32 + quad * 8);
        for (int nt = 0; nt < 24; ++nt) {
            floatx4 acc = {0.f, 0.f, 0.f, 0.f};
            const ushort_t* wb = wqkvT + (size_t)(nt * 16 + l15) * 128 + quad * 8;
            #pragma unroll
            for (int kt = 0; kt < 4; ++kt)
                acc = __builtin_amdgcn_mfma_f32_16x16x32_bf16(afrag[kt],
                        *(const short8*)(wb + kt * 32), acc, 0, 0, 0);
            int ncol = nt * 16 + l15;
            #pragma unroll
            for (int r = 0; r < 4; ++r) {
                int row = 16 * wv + quad * 4 + r;
                ushort_t val = f2bf(acc[r]);
                if (ncol < 128)      q_s[row * 136 + ncol] = val;
                else if (ncol < 256) k_s[row * 136 + (ncol - 128)] = val;
                else                 v_s[(ncol - 256) * 72 + row] = val;
            }
        }
    }
    __syncthreads();

    float pvals[2][4][4];
    #pragma unroll
    for (int head = 0; head < 2; ++head) {
        floatx4 sacc[4];
        #pragma unroll
        for (int nt = 0; nt < 4; ++nt) sacc[nt] = floatx4{0.f, 0.f, 0.f, 0.f};
        #pragma unroll
        for (int kt = 0; kt < 2; ++kt) {
            short8 aq = *(const short8*)(q_s + (16 * wv + l15) * 136 + head * 64 + kt * 32 + quad * 8);
            #pragma unroll
            for (int nt = 0; nt < 4; ++nt) {
                short8 bk = *(const short8*)(k_s + (nt * 16 + l15) * 136 + head * 64 + kt * 32 + quad * 8);
                sacc[nt] = __builtin_amdgcn_mfma_f32_16x16x32_bf16(aq, bk, sacc[nt], 0, 0, 0);
            }
        }
        #pragma unroll
        for (int r = 0; r < 4; ++r) {
            int qrow = 16 * wv + quad * 4 + r;
            int iq = qrow >> WwLog, jq = qrow & WwM1;
            float v[4], mx = -1e30f;
            #pragma unroll
            for (int nt = 0; nt < 4; ++nt) {
                int kcol = nt * 16 + l15;
                int ik = kcol >> WwLog, jk = kcol & WwM1;
                int idx = (iq - ik + WhM1) * biasMul + (jq - jk + WwM1);
                v[nt] = sacc[nt][r] * 0.125f + table[idx * 2 + head];
                mx = fmaxf(mx, v[nt]);
            }
            mx = fmaxf(mx, __shfl_xor(mx, 1)); mx = fmaxf(mx, __shfl_xor(mx, 2));
            mx = fmaxf(mx, __shfl_xor(mx, 4)); mx = fmaxf(mx, __shfl_xor(mx, 8));
            float e[4], sm = 0.f;
            #pragma unroll
            for (int nt = 0; nt < 4; ++nt) { e[nt] = __expf(v[nt] - mx); sm += e[nt]; }
            sm += __shfl_xor(sm, 1); sm += __shfl_xor(sm, 2);
            sm += __shfl_xor(sm, 4); sm += __shfl_xor(sm, 8);
            float inv = 1.f / sm;
            #pragma unroll
            for (int nt = 0; nt < 4; ++nt) pvals[head][nt][r] = e[nt] * inv;
        }
    }
    __syncthreads();

    {
        ushort_t* p_s = q_s;
        #pragma unroll
        for (int head = 0; head < 2; ++head)
            #pragma unroll
            for (int nt = 0; nt < 4; ++nt)
                #pragma unroll
                for (int r = 0; r < 4; ++r) {
                    int row = 16 * wv + quad * 4 + r;
                    p_s[(head * 64 + row) * 72 + nt * 16 + l15] = f2bf(pvals[head][nt][r]);
                }
    }
    LDS_ROUNDTRIP_FENCE();
    {
        const ushort_t* p_s = q_s;
        ushort_t* o_s = k_s;
        #pragma unroll
        for (int head = 0; head < 2; ++head) {
            short8 ap[2];
            #pragma unroll
            for (int kt = 0; kt < 2; ++kt)
                ap[kt] = *(const short8*)(p_s + (head * 64 + 16 * wv + l15) * 72 + kt * 32 + quad * 8);
            #pragma unroll
            for (int nt = 0; nt < 4; ++nt) {
                floatx4 acc = {0.f, 0.f, 0.f, 0.f};
                #pragma unroll
                for (int kt = 0; kt < 2; ++kt) {
                    short8 bv = *(const short8*)(v_s + (head * 64 + nt * 16 + l15) * 72 + kt * 32 + quad * 8);
                    acc = __builtin_amdgcn_mfma_f32_16x16x32_bf16(ap[kt], bv, acc, 0, 0, 0);
                }
                #pragma unroll
                for (int r = 0; r < 4; ++r)
                    o_s[(16 * wv + quad * 4 + r) * 136 + head * 64 + nt * 16 + l15] = f2bf(acc[r]);
            }
        }
    }
    __syncthreads();

    {
        const ushort_t* o_s = k_s;
        short8 ao[4];
        #pragma unroll
        for (int kt = 0; kt < 4; ++kt)
            ao[kt] = *(const short8*)(o_s + (16 * wv + l15) * 136 + kt * 32 + quad * 8);
        #pragma unroll
        for (int nt = 0; nt < 8; ++nt) {
            floatx4 acc = {0.f, 0.f, 0.f, 0.f};
            const ushort_t* wb = wpT + (size_t)(nt * 16 + l15) * 128 + quad * 8;
            #pragma unroll
            for (int kt = 0; kt < 4; ++kt)
                acc = __builtin_amdgcn_mfma_f32_16x16x32_bf16(ao[kt],
                        *(const short8*)(wb + kt * 32), acc, 0, 0, 0);
            int col = nt * 16 + l15;
            float bpv = bp[col];
            #pragma unroll
            for (int r = 0; r < 4; ++r) {
                int row = 16 * wv + quad * 4 + r;
                float res = acc[r] + bpv + bf2f(xw_s[row * 136 + col]);
                bout[(size_t)tok2p(row) * 256 + chOff + col] = f2bf(res);
            }
        }
    }
}

// ================= mlp_k v9: v4 structure verbatim + packed-cvt VALU diet only =========
// LDS 79872 B: x2_s [64][264] @0 (33792); wbuf @33792 (36864: w1 [64][264] / w2 [256][72]);
// hbuf [64][72] @70656 (9216). xn_s overlay on wbuf (transient). ot_s [256][72] overlay @0.
// All barriers are plain __syncthreads() (v7/v8 asm-barrier variant was 2.2x slower).
__global__ __launch_bounds__(256, 2) void mlp_k(
    const float* __restrict__ x,          // NCHW fp32
    const ushort_t* __restrict__ bout,    // NHWC bf16
    const float* __restrict__ g2, const float* __restrict__ b2,
    const ushort_t* __restrict__ w1p, const float* __restrict__ b1,
    const ushort_t* __restrict__ w2p, const float* __restrict__ bm2,
    float* __restrict__ out)
{
    __shared__ __align__(16) char smem_raw[79872];
    ushort_t* x2_s = (ushort_t*)smem_raw;               // [64][264]
    ushort_t* wbuf = (ushort_t*)(smem_raw + 33792);     // union w1/w2 chunk
    ushort_t* hbuf = (ushort_t*)(smem_raw + 70656);     // [64][72]
    ushort_t* xn_s = wbuf;                              // transient overlay
    ushort_t* ot_s = (ushort_t*)smem_raw;               // [256][72] epilogue overlay

    const int t = threadIdx.x;
    const int p0 = blockIdx.x * 64;
    const int wv = t >> 6, lane = t & 63, l31 = lane & 31, half = lane >> 5;

    {   // x fp32 NCHW tile -> x2_s bf16 (packed cvt)
        const int pg = t & 15, cb = t >> 4;
        for (int it = 0; it < 16; ++it) {
            int c = cb + 16 * it;
            floatx4 v = *(const floatx4*)(x + (size_t)c * 65536 + p0 + pg * 4);
            unsigned int pk01 = f2bf2(v[0], v[1]);
            unsigned int pk23 = f2bf2(v[2], v[3]);
            x2_s[(pg * 4 + 0) * 264 + c] = (ushort_t)pk01;
            x2_s[(pg * 4 + 1) * 264 + c] = (ushort_t)(pk01 >> 16);
            x2_s[(pg * 4 + 2) * 264 + c] = (ushort_t)pk23;
            x2_s[(pg * 4 + 3) * 264 + c] = (ushort_t)(pk23 >> 16);
        }
    }
    __syncthreads();
    {   // x2 = x + bout; LN2 -> xn_s (packed cvt)
        const int row = t >> 2, part = t & 3;
        float vals[64];
        float s = 0.f, ss = 0.f;
        const ushort_t* bpr = bout + (size_t)(p0 + row) * 256 + part * 64;
        ushort_t* xpr = x2_s + row * 264 + part * 64;
        #pragma unroll
        for (int k8 = 0; k8 < 8; ++k8) {
            u32x4 bv = *(const u32x4*)(bpr + k8 * 8);
            u32x4 xv = *(const u32x4*)(xpr + k8 * 8);
            const ushort_t* pb = (const ushort_t*)&bv;
            const ushort_t* px = (const ushort_t*)&xv;
            #pragma unroll
            for (int k = 0; k < 8; ++k) {
                float v = bf2f(px[k]) + bf2f(pb[k]);
                vals[k8 * 8 + k] = v; s += v; ss += v * v;
            }
        }
        s  += __shfl_xor(s, 1);  s  += __shfl_xor(s, 2);
        ss += __shfl_xor(ss, 1); ss += __shfl_xor(ss, 2);
        float mean = s * (1.f / 256.f);
        float rstd = rsqrtf(ss * (1.f / 256.f) - mean * mean + 1e-5f);
        const float* g2p = g2 + part * 64;
        const float* b2p = b2 + part * 64;
        ushort_t* npr = xn_s + row * 264 + part * 64;
        #pragma unroll
        for (int k8 = 0; k8 < 8; ++k8) {
            alignas(16) unsigned int o4[4], n4[4];
            #pragma unroll
            for (int kk = 0; kk < 4; ++kk) {
                float v0 = vals[k8 * 8 + kk * 2];
                float v1 = vals[k8 * 8 + kk * 2 + 1];
                o4[kk] = f2bf2(v0, v1);
                int cc = k8 * 8 + kk * 2;
                n4[kk] = f2bf2((v0 - mean) * rstd * g2p[cc]     + b2p[cc],
                               (v1 - mean) * rstd * g2p[cc + 1] + b2p[cc + 1]);
            }
            *(u32x4*)(xpr + k8 * 8) = *(const u32x4*)o4;
            *(u32x4*)(npr + k8 * 8) = *(const u32x4*)n4;
        }
    }
    __syncthreads();

    // GEMM1 wave tile: rows 32*g1m..+31, hidden cols 32*g1n..+31 of the 64-col chunk
    const int g1m = wv & 1, g1n = wv >> 1;
    // GEMM2 wave tiles: rows 32*g2m..+31, out cols g2nb + {0,32,64,96}
    const int g2m = wv & 1;
    const int g2nb = 128 * (wv >> 1);

    short8 afrag[16];    // xn rows (32) x K=256, register-resident
    #pragma unroll
    for (int ks = 0; ks < 16; ++ks)
        afrag[ks] = *(const short8*)(xn_s + (32 * g1m + l31) * 264 + ks * 16 + half * 8);

    u32x4* wb16 = (u32x4*)wbuf;
    u32x4 w1reg[9], w2reg[9];
    {   // w1[0] chunk: 33792 B = 2112 u32x4 = 8*256 + 64
        const u32x4* s1 = (const u32x4*)w1p;
        #pragma unroll
        for (int j = 0; j < 8; ++j) w1reg[j] = s1[j * 256 + t];
        if (t < 64) w1reg[8] = s1[2048 + t];
    }
    __syncthreads();   // all afrag reads done (xn_s dead)
    {
        #pragma unroll
        for (int j = 0; j < 8; ++j) wb16[j * 256 + t] = w1reg[j];
        if (t < 64) wb16[2048 + t] = w1reg[8];
    }
    __syncthreads();   // wbuf = w1[0]

    floatx16 oacc[4];
    #pragma unroll
    for (int nt = 0; nt < 4; ++nt)
        #pragma unroll
        for (int i = 0; i < 16; ++i) oacc[nt][i] = 0.f;

    for (int ch = 0; ch < 16; ++ch) {
        {   // prefetch w2[ch] into regs (covered by GEMM1): 36864 B = 2304 u32x4 = 9*256
            const u32x4* s2 = (const u32x4*)(w2p + (size_t)ch * 18432);
            #pragma unroll
            for (int j = 0; j < 9; ++j) w2reg[j] = s2[j * 256 + t];
        }
        // ---- GEMM1: H-chunk = xn @ w1[ch], two interleaved accumulator chains
        floatx16 ha, hb;
        #pragma unroll
        for (int i = 0; i < 16; ++i) { ha[i] = 0.f; hb[i] = 0.f; }
        #pragma unroll
        for (int ks = 0; ks < 16; ks += 2) {
            short8 bf0 = *(const short8*)(wbuf + (32 * g1n + l31) * 264 + ks * 16 + half * 8);
            short8 bf1 = *(const short8*)(wbuf + (32 * g1n + l31) * 264 + ks * 16 + 16 + half * 8);
            ha = __builtin_amdgcn_mfma_f32_32x32x16_bf16(afrag[ks], bf0, ha, 0, 0, 0);
            hb = __builtin_amdgcn_mfma_f32_32x32x16_bf16(afrag[ks + 1], bf1, hb, 0, 0, 0);
        }
        {   // bias + GELU -> hbuf (packed converts)
            float bb = b1[ch * 64 + 32 * g1n + l31];
            int col = 32 * g1n + l31;
            #pragma unroll
            for (int r = 0; r < 16; r += 2) {
                float v0 = gelu_f(ha[r] + hb[r] + bb);
                float v1 = gelu_f(ha[r + 1] + hb[r + 1] + bb);
                unsigned int pk = f2bf2(v0, v1);
                int row0 = 32 * g1m + (r & 3) + 8 * (r >> 2) + 4 * half;
                hbuf[row0 * 72 + col]       = (ushort_t)pk;
                hbuf[(row0 + 1) * 72 + col] = (ushort_t)(pk >> 16);
            }
        }
        __syncthreads();                         // B1: w1 reads + hbuf writes done
        {
            #pragma unroll
            for (int j = 0; j < 9; ++j) wb16[j * 256 + t] = w2reg[j];
        }
        __syncthreads();                         // B2: wbuf = w2[ch]
        if (ch < 15) {   // prefetch w1[ch+1] (covered by GEMM2)
            const u32x4* s1 = (const u32x4*)(w1p + (size_t)(ch + 1) * 16896);
            #pragma unroll
            for (int j = 0; j < 8; ++j) w1reg[j] = s1[j * 256 + t];
            if (t < 64) w1reg[8] = s1[2048 + t];
        }
        // ---- GEMM2: out += H @ w2[ch]
        #pragma unroll
        for (int ks = 0; ks < 4; ++ks) {
            short8 haf = *(const short8*)(hbuf + (32 * g2m + l31) * 72 + ks * 16 + half * 8);
            #pragma unroll
            for (int nt = 0; nt < 4; ++nt) {
                short8 bfr = *(const short8*)(wbuf + (g2nb + 32 * nt + l31) * 72 + ks * 16 + half * 8);
                oacc[nt] = __builtin_amdgcn_mfma_f32_32x32x16_bf16(haf, bfr, oacc[nt], 0, 0, 0);
            }
        }
        __syncthreads();                         // B3: w2 + hbuf reads done
        if (ch < 15) {
            #pragma unroll
            for (int j = 0; j < 8; ++j) wb16[j * 256 + t] = w1reg[j];
            if (t < 64) wb16[2048 + t] = w1reg[8];
        }
        __syncthreads();                         // B4: wbuf = w1[ch+1]
    }

    // epilogue: + bm2 + x2 residual
    #pragma unroll
    for (int nt = 0; nt < 4; ++nt) {
        int col = g2nb + 32 * nt + l31;
        float bb = bm2[col];
        #pragma unroll
        for (int r = 0; r < 16; ++r) {
            int row = 32 * g2m + (r & 3) + 8 * (r >> 2) + 4 * half;
            oacc[nt][r] += bb + bf2f(x2_s[row * 264 + col]);
        }
    }
    __syncthreads();   // x2_s/wbuf dead -> ot_s overlay safe
    #pragma unroll
    for (int nt = 0; nt < 4; ++nt) {
        int col = g2nb + 32 * nt + l31;
        #pragma unroll
        for (int r = 0; r < 16; r += 2) {
            int row0 = 32 * g2m + (r & 3) + 8 * (r >> 2) + 4 * half;   // even
            *(unsigned int*)(ot_s + col * 72 + row0) = f2bf2(oacc[nt][r], oacc[nt][r + 1]);
        }
    }
    __syncthreads();
    {   // coalesced fp32 NCHW store: pixel-per-lane, channel per iteration
        for (int it = 0; it < 64; ++it) {
            int c = it * 4 + wv;
            out[(size_t)c * 65536 + p0 + lane] = bf2f(ot_s[c * 72 + lane]);
        }
    }
}

extern "C" void kernel_launch(void* const* d_in, const int* in_sizes, int n_in,
                              void* d_out, int out_size, void* d_ws, size_t ws_size,
                              hipStream_t stream) {
    (void)in_sizes; (void)n_in; (void)out_size; (void)ws_size;
    const float* x     = (const float*)d_in[0];
    const float* n1g   = (const float*)d_in[1];
    const float* n1b   = (const float*)d_in[2];
    const float* qkv_r = (const float*)d_in[3];
    const float* pr_w  = (const float*)d_in[4];
    const float* pr_b  = (const float*)d_in[5];
    const float* tab_r = (const float*)d_in[6];
    const float* qkv_a = (const float*)d_in[7];
    const float* pa_w  = (const float*)d_in[8];
    const float* pa_b  = (const float*)d_in[9];
    const float* tab_a = (const float*)d_in[10];
    const float* n2g   = (const float*)d_in[11];
    const float* n2b   = (const float*)d_in[12];
    const float* w1    = (const float*)d_in[13];
    const float* b1    = (const float*)d_in[14];
    const float* w2    = (const float*)d_in[15];
    const float* b2    = (const float*)d_in[16];

    char* ws = (char*)d_ws;
    ushort_t* wqkvT_r = (ushort_t*)(ws);              //  98304 B
    ushort_t* wqkvT_a = (ushort_t*)(ws + 98304);      //  98304 B
    ushort_t* wpT_r   = (ushort_t*)(ws + 196608);     //  32768 B
    ushort_t* wpT_a   = (ushort_t*)(ws + 229376);     //  32768 B
    ushort_t* w1p     = (ushort_t*)(ws + 262144);     // 540672 B  [16][64][264]
    ushort_t* w2p     = (ushort_t*)(ws + 802816);     // 589824 B  [16][256][72]
    ushort_t* bout    = (ushort_t*)(ws + 1392640);    // 33554432 B
    ushort_t* xn      = (ushort_t*)d_out;             // staged in d_out (dead before mlp_k)

    prep_k<<<1664, 256, 0, stream>>>(x, n1g, n1b, xn,
                                     qkv_r, wqkvT_r, qkv_a, wqkvT_a,
                                     pr_w, wpT_r, pa_w, wpT_a,
                                     w1, w1p, w2, w2p);
    attn_k<<<dim3(1024, 2), 256, 0, stream>>>(xn, wqkvT_r, wpT_r, pr_b, tab_r,
                                              wqkvT_a, wpT_a, pa_b, tab_a, bout);
    mlp_k<<<1024, 256, 0, stream>>>(x, bout, n2g, n2b, w1p, b1, w2p, b2, (float*)d_out);
}

// Round 6
// 363.049 us; speedup vs baseline: 1.7394x; 1.1711x over previous
//
#include <hip/hip_runtime.h>
#include <stdint.h>

typedef unsigned short ushort_t;
typedef __attribute__((ext_vector_type(8))) short short8;       // 8 x bf16 (MFMA A/B frag)
typedef __attribute__((ext_vector_type(4))) float floatx4;      // 16x16 C frag / 16B fp32
typedef __attribute__((ext_vector_type(16))) float floatx16;    // 32x32 C frag
typedef __attribute__((ext_vector_type(4))) unsigned int u32x4; // 16B vector

__device__ __forceinline__ float bf2f(ushort_t u) {
    union { unsigned int i; float f; } v; v.i = ((unsigned int)u) << 16; return v.f;
}
__device__ __forceinline__ ushort_t f2bf(float f) {
    union { float ff; unsigned int i; } v; v.ff = f;
    unsigned int x = v.i;
    return (ushort_t)((x + 0x7fffu + ((x >> 16) & 1u)) >> 16);  // RNE
}
// Packed RNE fp32x2 -> bf16x2 (lo = a, hi = b). Same rounding as f2bf (verified R4/R5 runs).
__device__ __forceinline__ unsigned int f2bf2(float a, float b) {
    unsigned int r;
    asm("v_cvt_pk_bf16_f32 %0, %1, %2" : "=v"(r) : "v"(a), "v"(b));
    return r;
}
__device__ __forceinline__ float gelu_f(float v) {
    // 0.5v(1+tanh(u)) == v * sigmoid(2u)  (verified within harness tolerance, R4/R5 runs)
    float u = v * (0.7978845608f + 0.0356774081f * v * v);
    return v * __fdividef(1.f, 1.f + __expf(-2.f * u));
}
#define LDS_ROUNDTRIP_FENCE() __asm__ volatile("s_waitcnt lgkmcnt(0)" ::: "memory")
// NOTE (journal): the asm "s_waitcnt lgkmcnt(0); s_barrier" barrier used in v7/v8 correlates
// with a 2.2x mlp_k slowdown vs plain __syncthreads() at identical structure (166 -> 365us,
// pure stall: MFMA/VALU time unchanged). Plain __syncthreads() everywhere.

// ================= prep_k: ln1 (blocks 0..1023) + all weight preps (1024..1663) ==========
__global__ __launch_bounds__(256) void prep_k(
    const float* __restrict__ x, const float* __restrict__ n1g, const float* __restrict__ n1b,
    ushort_t* __restrict__ xn,
    const float* __restrict__ qkv_r, ushort_t* __restrict__ wqkvT_r,
    const float* __restrict__ qkv_a, ushort_t* __restrict__ wqkvT_a,
    const float* __restrict__ pr_w,  ushort_t* __restrict__ wpT_r,
    const float* __restrict__ pa_w,  ushort_t* __restrict__ wpT_a,
    const float* __restrict__ w1,    ushort_t* __restrict__ w1p,
    const float* __restrict__ w2,    ushort_t* __restrict__ w2p)
{
    __shared__ __align__(16) char pshm[33792];
    const int t = threadIdx.x;
    int b = blockIdx.x;
    if (b < 1024) {
        // ---- LN1 + NCHW(fp32) -> NHWC(bf16) ----
        ushort_t* tile = (ushort_t*)pshm;    // [64][264]
        const int p0 = b * 64;
        {
            const int pg = t & 15, cb = t >> 4;
            for (int it = 0; it < 16; ++it) {
                int c = cb + 16 * it;
                floatx4 v = *(const floatx4*)(x + (size_t)c * 65536 + p0 + pg * 4);
                unsigned int pk01 = f2bf2(v[0], v[1]);
                unsigned int pk23 = f2bf2(v[2], v[3]);
                tile[(pg * 4 + 0) * 264 + c] = (ushort_t)pk01;
                tile[(pg * 4 + 1) * 264 + c] = (ushort_t)(pk01 >> 16);
                tile[(pg * 4 + 2) * 264 + c] = (ushort_t)pk23;
                tile[(pg * 4 + 3) * 264 + c] = (ushort_t)(pk23 >> 16);
            }
        }
        __syncthreads();
        const int pix = t >> 2, part = t & 3;
        float vals[64];
        float s = 0.f, ss = 0.f;
        #pragma unroll
        for (int k = 0; k < 64; ++k) {
            float v = bf2f(tile[pix * 264 + part * 64 + k]);
            vals[k] = v; s += v; ss += v * v;
        }
        s  += __shfl_xor(s, 1);  s  += __shfl_xor(s, 2);
        ss += __shfl_xor(ss, 1); ss += __shfl_xor(ss, 2);
        float mean = s * (1.f / 256.f);
        float rstd = rsqrtf(ss * (1.f / 256.f) - mean * mean + 1e-5f);
        size_t obase = (size_t)(p0 + pix) * 256 + part * 64;
        #pragma unroll
        for (int k8 = 0; k8 < 8; ++k8) {
            alignas(16) unsigned int o4[4];
            #pragma unroll
            for (int kk = 0; kk < 4; ++kk) {
                int c = part * 64 + k8 * 8 + kk * 2;
                float f0 = (vals[k8 * 8 + kk * 2]     - mean) * rstd * n1g[c]     + n1b[c];
                float f1 = (vals[k8 * 8 + kk * 2 + 1] - mean) * rstd * n1g[c + 1] + n1b[c + 1];
                o4[kk] = f2bf2(f0, f1);
            }
            *(u32x4*)(xn + obase + k8 * 8) = *(const u32x4*)o4;
        }
        return;
    }
    b -= 1024;
    if (b < 512) {
        // ---- simple transposes fp32 [R][C] -> bf16 [C][R] ----
        const float* src; ushort_t* dst; int R, C, bi;
        if (b < 192)      { src = qkv_r; dst = wqkvT_r; R = 128; C = 384; bi = b;       }
        else if (b < 384) { src = qkv_a; dst = wqkvT_a; R = 128; C = 384; bi = b - 192; }
        else if (b < 448) { src = pr_w;  dst = wpT_r;   R = 128; C = 128; bi = b - 384; }
        else              { src = pa_w;  dst = wpT_a;   R = 128; C = 128; bi = b - 448; }
        int nbx = C / 16;
        int c0 = (bi % nbx) * 16, r0 = (bi / nbx) * 16;
        float* ts = (float*)pshm;    // [16][17]
        int tx = t & 15, ty = t >> 4;
        ts[ty * 17 + tx] = src[(size_t)(r0 + ty) * C + (c0 + tx)];
        __syncthreads();
        dst[(size_t)(c0 + ty) * R + (r0 + tx)] = f2bf(ts[tx * 17 + ty]);
        return;
    }
    b -= 512;
    float* s = (float*)pshm;   // [64][65]
    if (b < 64) {
        // ---- w1prep: w1 fp32 [256][1024] -> [16][64][264] ----
        const int ch = b & 15, k0 = (b >> 4) * 64;
        {
            int nn = t & 63, kr = t >> 6;
            for (int j = 0; j < 16; ++j) {
                int kk = j * 4 + kr;
                s[kk * 65 + nn] = w1[(size_t)(k0 + kk) * 1024 + ch * 64 + nn];
            }
        }
        __syncthreads();
        {
            int kk = t & 63, nr = t >> 6;
            for (int j = 0; j < 16; ++j) {
                int n2 = j * 4 + nr;
                w1p[(size_t)ch * 16896 + n2 * 264 + k0 + kk] = f2bf(s[kk * 65 + n2]);
            }
        }
        return;
    }
    b -= 64;
    {
        // ---- w2prep: w2 fp32 [1024][256] -> [16][256][72] ----
        const int ch = b & 15, n0 = (b >> 4) * 64;
        {
            int nn = t & 63, kr = t >> 6;
            for (int j = 0; j < 16; ++j) {
                int kk = j * 4 + kr;
                s[kk * 65 + nn] = w2[(size_t)(ch * 64 + kk) * 256 + n0 + nn];
            }
        }
        __syncthreads();
        {
            int kk = t & 63, nr = t >> 6;
            for (int j = 0; j < 16; ++j) {
                int n2 = j * 4 + nr;
                w2p[(size_t)ch * 18432 + (n0 + n2) * 72 + kk] = f2bf(s[kk * 65 + n2]);
            }
        }
    }
}

// ================= attn_k v10: N-split QKV/proj (B-frag load : MFMA = 1:4) ==============
// Wave decomposition change vs v9: in the QKV and proj GEMMs each wave owns ALL 64 rows
// (afrag for 4 M-tiles, register-resident) and a column slice (96 cols QKV / 32 cols proj).
// Each global B-fragment load now feeds 4 MFMAs (was 1), and per-block L2 weight traffic
// drops 4x. S/softmax/PV phases and all LDS layouts unchanged.
__global__ __launch_bounds__(256, 2) void attn_k(
    const ushort_t* __restrict__ xn,
    const ushort_t* __restrict__ wqkvT_r, const ushort_t* __restrict__ wpT_r,
    const float* __restrict__ bp_r, const float* __restrict__ table_r,
    const ushort_t* __restrict__ wqkvT_a, const ushort_t* __restrict__ wpT_a,
    const float* __restrict__ bp_a, const float* __restrict__ table_a,
    ushort_t* __restrict__ bout)
{
    __shared__ __align__(16) char smem_raw[71680];
    ushort_t* xw_s = (ushort_t*)smem_raw;                   // [64][136]
    ushort_t* q_s  = (ushort_t*)(smem_raw + 17408);         // q [64][136] / P [2][64][72]
    ushort_t* k_s  = (ushort_t*)(smem_raw + 35840);         // k [64][136] / O [64][136]
    ushort_t* v_s  = (ushort_t*)(smem_raw + 53248);         // vT [128][72]

    const int br  = blockIdx.y;
    const int wid = blockIdx.x;
    const int t = threadIdx.x;
    const int wv = t >> 6, lane = t & 63, l15 = lane & 15, quad = lane >> 4;

    const int WwLog = br ? 4 : 2;
    const int WhLog = br ? 2 : 4;
    const int nWxLog = 8 - WwLog;
    const int wx = wid & ((1 << nWxLog) - 1);
    const int wy = wid >> nWxLog;
    const int chOff = br ? 128 : 0;
    const int WwM1 = (1 << WwLog) - 1, WhM1 = (1 << WhLog) - 1;
    const int biasMul = 2 * (1 << WwLog) - 1;
    const ushort_t* wqkvT = br ? wqkvT_a : wqkvT_r;
    const ushort_t* wpT   = br ? wpT_a   : wpT_r;
    const float* bp    = br ? bp_a    : bp_r;
    const float* table = br ? table_a : table_r;

    auto tok2p = [&](int n) -> int {
        int i = n >> WwLog, j = n & WwM1;
        return ((wy << WhLog) + i) * 256 + (wx << WwLog) + j;
    };

    {
        int tok = t >> 2, seg = t & 3;
        const ushort_t* src = xn + (size_t)tok2p(tok) * 256 + chOff + seg * 32;
        ushort_t* dst = xw_s + tok * 136 + seg * 32;
        *(u32x4*)(dst)      = *(const u32x4*)(src);
        *(u32x4*)(dst + 8)  = *(const u32x4*)(src + 8);
        *(u32x4*)(dst + 16) = *(const u32x4*)(src + 16);
        *(u32x4*)(dst + 24) = *(const u32x4*)(src + 24);
    }
    __syncthreads();

    {   // ---- QKV GEMM, N-split: this wave computes cols [wv*96, wv*96+96) for all 64 rows
        short8 afrag[4][4];   // [Mtile][kt] : all 64 rows of xw
        #pragma unroll
        for (int mt = 0; mt < 4; ++mt)
            #pragma unroll
            for (int kt = 0; kt < 4; ++kt)
                afrag[mt][kt] = *(const short8*)(xw_s + (16 * mt + l15) * 136 + kt * 32 + quad * 8);
        #pragma unroll
        for (int ntl = 0; ntl < 6; ++ntl) {
            int nt = wv * 6 + ntl;
            int ncol = nt * 16 + l15;
            const ushort_t* wb = wqkvT + (size_t)ncol * 128 + quad * 8;
            short8 bfr[4];
            #pragma unroll
            for (int kt = 0; kt < 4; ++kt) bfr[kt] = *(const short8*)(wb + kt * 32);
            #pragma unroll
            for (int mt = 0; mt < 4; ++mt) {
                floatx4 acc = {0.f, 0.f, 0.f, 0.f};
                #pragma unroll
                for (int kt = 0; kt < 4; ++kt)
                    acc = __builtin_amdgcn_mfma_f32_16x16x32_bf16(afrag[mt][kt], bfr[kt], acc, 0, 0, 0);
                #pragma unroll
                for (int r = 0; r < 4; ++r) {
                    int row = 16 * mt + quad * 4 + r;
                    ushort_t val = f2bf(acc[r]);
                    if (ncol < 128)      q_s[row * 136 + ncol] = val;
                    else if (ncol < 256) k_s[row * 136 + (ncol - 128)] = val;
                    else                 v_s[(ncol - 256) * 72 + row] = val;
                }
            }
        }
    }
    __syncthreads();

    float pvals[2][4][4];
    #pragma unroll
    for (int head = 0; head < 2; ++head) {
        floatx4 sacc[4];
        #pragma unroll
        for (int nt = 0; nt < 4; ++nt) sacc[nt] = floatx4{0.f, 0.f, 0.f, 0.f};
        #pragma unroll
        for (int kt = 0; kt < 2; ++kt) {
            short8 aq = *(const short8*)(q_s + (16 * wv + l15) * 136 + head * 64 + kt * 32 + quad * 8);
            #pragma unroll
            for (int nt = 0; nt < 4; ++nt) {
                short8 bk = *(const short8*)(k_s + (nt * 16 + l15) * 136 + head * 64 + kt * 32 + quad * 8);
                sacc[nt] = __builtin_amdgcn_mfma_f32_16x16x32_bf16(aq, bk, sacc[nt], 0, 0, 0);
            }
        }
        #pragma unroll
        for (int r = 0; r < 4; ++r) {
            int qrow = 16 * wv + quad * 4 + r;
            int iq = qrow >> WwLog, jq = qrow & WwM1;
            float v[4], mx = -1e30f;
            #pragma unroll
            for (int nt = 0; nt < 4; ++nt) {
                int kcol = nt * 16 + l15;
                int ik = kcol >> WwLog, jk = kcol & WwM1;
                int idx = (iq - ik + WhM1) * biasMul + (jq - jk + WwM1);
                v[nt] = sacc[nt][r] * 0.125f + table[idx * 2 + head];
                mx = fmaxf(mx, v[nt]);
            }
            mx = fmaxf(mx, __shfl_xor(mx, 1)); mx = fmaxf(mx, __shfl_xor(mx, 2));
            mx = fmaxf(mx, __shfl_xor(mx, 4)); mx = fmaxf(mx, __shfl_xor(mx, 8));
            float e[4], sm = 0.f;
            #pragma unroll
            for (int nt = 0; nt < 4; ++nt) { e[nt] = __expf(v[nt] - mx); sm += e[nt]; }
            sm += __shfl_xor(sm, 1); sm += __shfl_xor(sm, 2);
            sm += __shfl_xor(sm, 4); sm += __shfl_xor(sm, 8);
            float inv = 1.f / sm;
            #pragma unroll
            for (int nt = 0; nt < 4; ++nt) pvals[head][nt][r] = e[nt] * inv;
        }
    }
    __syncthreads();

    {
        ushort_t* p_s = q_s;
        #pragma unroll
        for (int head = 0; head < 2; ++head)
            #pragma unroll
            for (int nt = 0; nt < 4; ++nt)
                #pragma unroll
                for (int r = 0; r < 4; ++r) {
                    int row = 16 * wv + quad * 4 + r;
                    p_s[(head * 64 + row) * 72 + nt * 16 + l15] = f2bf(pvals[head][nt][r]);
                }
    }
    LDS_ROUNDTRIP_FENCE();
    {
        const ushort_t* p_s = q_s;
        ushort_t* o_s = k_s;
        #pragma unroll
        for (int head = 0; head < 2; ++head) {
            short8 ap[2];
            #pragma unroll
            for (int kt = 0; kt < 2; ++kt)
                ap[kt] = *(const short8*)(p_s + (head * 64 + 16 * wv + l15) * 72 + kt * 32 + quad * 8);
            #pragma unroll
            for (int nt = 0; nt < 4; ++nt) {
                floatx4 acc = {0.f, 0.f, 0.f, 0.f};
                #pragma unroll
                for (int kt = 0; kt < 2; ++kt) {
                    short8 bv = *(const short8*)(v_s + (head * 64 + nt * 16 + l15) * 72 + kt * 32 + quad * 8);
                    acc = __builtin_amdgcn_mfma_f32_16x16x32_bf16(ap[kt], bv, acc, 0, 0, 0);
                }
                #pragma unroll
                for (int r = 0; r < 4; ++r)
                    o_s[(16 * wv + quad * 4 + r) * 136 + head * 64 + nt * 16 + l15] = f2bf(acc[r]);
            }
        }
    }
    __syncthreads();

    {   // ---- proj GEMM, N-split: this wave computes cols [wv*32, wv*32+32) for all 64 rows
        const ushort_t* o_s = k_s;
        short8 ao[4][4];
        #pragma unroll
        for (int mt = 0; mt < 4; ++mt)
            #pragma unroll
            for (int kt = 0; kt < 4; ++kt)
                ao[mt][kt] = *(const short8*)(o_s + (16 * mt + l15) * 136 + kt * 32 + quad * 8);
        #pragma unroll
        for (int ntl = 0; ntl < 2; ++ntl) {
            int nt = wv * 2 + ntl;
            int col = nt * 16 + l15;
            const ushort_t* wb = wpT + (size_t)col * 128 + quad * 8;
            short8 bfr[4];
            #pragma unroll
            for (int kt = 0; kt < 4; ++kt) bfr[kt] = *(const short8*)(wb + kt * 32);
            float bpv = bp[col];
            #pragma unroll
            for (int mt = 0; mt < 4; ++mt) {
                floatx4 acc = {0.f, 0.f, 0.f, 0.f};
                #pragma unroll
                for (int kt = 0; kt < 4; ++kt)
                    acc = __builtin_amdgcn_mfma_f32_16x16x32_bf16(ao[mt][kt], bfr[kt], acc, 0, 0, 0);
                #pragma unroll
                for (int r = 0; r < 4; ++r) {
                    int row = 16 * mt + quad * 4 + r;
                    float res = acc[r] + bpv + bf2f(xw_s[row * 136 + col]);
                    bout[(size_t)tok2p(row) * 256 + chOff + col] = f2bf(res);
                }
            }
        }
    }
}

// ================= mlp_k v9 (frozen): v4 structure + packed-cvt VALU diet =========
// LDS 79872 B: x2_s [64][264] @0 (33792); wbuf @33792 (36864: w1 [64][264] / w2 [256][72]);
// hbuf [64][72] @70656 (9216). xn_s overlay on wbuf (transient). ot_s [256][72] overlay @0.
__global__ __launch_bounds__(256, 2) void mlp_k(
    const float* __restrict__ x,          // NCHW fp32
    const ushort_t* __restrict__ bout,    // NHWC bf16
    const float* __restrict__ g2, const float* __restrict__ b2,
    const ushort_t* __restrict__ w1p, const float* __restrict__ b1,
    const ushort_t* __restrict__ w2p, const float* __restrict__ bm2,
    float* __restrict__ out)
{
    __shared__ __align__(16) char smem_raw[79872];
    ushort_t* x2_s = (ushort_t*)smem_raw;               // [64][264]
    ushort_t* wbuf = (ushort_t*)(smem_raw + 33792);     // union w1/w2 chunk
    ushort_t* hbuf = (ushort_t*)(smem_raw + 70656);     // [64][72]
    ushort_t* xn_s = wbuf;                              // transient overlay
    ushort_t* ot_s = (ushort_t*)smem_raw;               // [256][72] epilogue overlay

    const int t = threadIdx.x;
    const int p0 = blockIdx.x * 64;
    const int wv = t >> 6, lane = t & 63, l31 = lane & 31, half = lane >> 5;

    {   // x fp32 NCHW tile -> x2_s bf16 (packed cvt)
        const int pg = t & 15, cb = t >> 4;
        for (int it = 0; it < 16; ++it) {
            int c = cb + 16 * it;
            floatx4 v = *(const floatx4*)(x + (size_t)c * 65536 + p0 + pg * 4);
            unsigned int pk01 = f2bf2(v[0], v[1]);
            unsigned int pk23 = f2bf2(v[2], v[3]);
            x2_s[(pg * 4 + 0) * 264 + c] = (ushort_t)pk01;
            x2_s[(pg * 4 + 1) * 264 + c] = (ushort_t)(pk01 >> 16);
            x2_s[(pg * 4 + 2) * 264 + c] = (ushort_t)pk23;
            x2_s[(pg * 4 + 3) * 264 + c] = (ushort_t)(pk23 >> 16);
        }
    }
    __syncthreads();
    {   // x2 = x + bout; LN2 -> xn_s (packed cvt)
        const int row = t >> 2, part = t & 3;
        float vals[64];
        float s = 0.f, ss = 0.f;
        const ushort_t* bpr = bout + (size_t)(p0 + row) * 256 + part * 64;
        ushort_t* xpr = x2_s + row * 264 + part * 64;
        #pragma unroll
        for (int k8 = 0; k8 < 8; ++k8) {
            u32x4 bv = *(const u32x4*)(bpr + k8 * 8);
            u32x4 xv = *(const u32x4*)(xpr + k8 * 8);
            const ushort_t* pb = (const ushort_t*)&bv;
            const ushort_t* px = (const ushort_t*)&xv;
            #pragma unroll
            for (int k = 0; k < 8; ++k) {
                float v = bf2f(px[k]) + bf2f(pb[k]);
                vals[k8 * 8 + k] = v; s += v; ss += v * v;
            }
        }
        s  += __shfl_xor(s, 1);  s  += __shfl_xor(s, 2);
        ss += __shfl_xor(ss, 1); ss += __shfl_xor(ss, 2);
        float mean = s * (1.f / 256.f);
        float rstd = rsqrtf(ss * (1.f / 256.f) - mean * mean + 1e-5f);
        const float* g2p = g2 + part * 64;
        const float* b2p = b2 + part * 64;
        ushort_t* npr = xn_s + row * 264 + part * 64;
        #pragma unroll
        for (int k8 = 0; k8 < 8; ++k8) {
            alignas(16) unsigned int o4[4], n4[4];
            #pragma unroll
            for (int kk = 0; kk < 4; ++kk) {
                float v0 = vals[k8 * 8 + kk * 2];
                float v1 = vals[k8 * 8 + kk * 2 + 1];
                o4[kk] = f2bf2(v0, v1);
                int cc = k8 * 8 + kk * 2;
                n4[kk] = f2bf2((v0 - mean) * rstd * g2p[cc]     + b2p[cc],
                               (v1 - mean) * rstd * g2p[cc + 1] + b2p[cc + 1]);
            }
            *(u32x4*)(xpr + k8 * 8) = *(const u32x4*)o4;
            *(u32x4*)(npr + k8 * 8) = *(const u32x4*)n4;
        }
    }
    __syncthreads();

    // GEMM1 wave tile: rows 32*g1m..+31, hidden cols 32*g1n..+31 of the 64-col chunk
    const int g1m = wv & 1, g1n = wv >> 1;
    // GEMM2 wave tiles: rows 32*g2m..+31, out cols g2nb + {0,32,64,96}
    const int g2m = wv & 1;
    const int g2nb = 128 * (wv >> 1);

    short8 afrag[16];    // xn rows (32) x K=256, register-resident
    #pragma unroll
    for (int ks = 0; ks < 16; ++ks)
        afrag[ks] = *(const short8*)(xn_s + (32 * g1m + l31) * 264 + ks * 16 + half * 8);

    u32x4* wb16 = (u32x4*)wbuf;
    u32x4 w1reg[9], w2reg[9];
    {   // w1[0] chunk: 33792 B = 2112 u32x4 = 8*256 + 64
        const u32x4* s1 = (const u32x4*)w1p;
        #pragma unroll
        for (int j = 0; j < 8; ++j) w1reg[j] = s1[j * 256 + t];
        if (t < 64) w1reg[8] = s1[2048 + t];
    }
    __syncthreads();   // all afrag reads done (xn_s dead)
    {
        #pragma unroll
        for (int j = 0; j < 8; ++j) wb16[j * 256 + t] = w1reg[j];
        if (t < 64) wb16[2048 + t] = w1reg[8];
    }
    __syncthreads();   // wbuf = w1[0]

    floatx16 oacc[4];
    #pragma unroll
    for (int nt = 0; nt < 4; ++nt)
        #pragma unroll
        for (int i = 0; i < 16; ++i) oacc[nt][i] = 0.f;

    for (int ch = 0; ch < 16; ++ch) {
        {   // prefetch w2[ch] into regs (covered by GEMM1): 36864 B = 2304 u32x4 = 9*256
            const u32x4* s2 = (const u32x4*)(w2p + (size_t)ch * 18432);
            #pragma unroll
            for (int j = 0; j < 9; ++j) w2reg[j] = s2[j * 256 + t];
        }
        // ---- GEMM1: H-chunk = xn @ w1[ch], two interleaved accumulator chains
        floatx16 ha, hb;
        #pragma unroll
        for (int i = 0; i < 16; ++i) { ha[i] = 0.f; hb[i] = 0.f; }
        #pragma unroll
        for (int ks = 0; ks < 16; ks += 2) {
            short8 bf0 = *(const short8*)(wbuf + (32 * g1n + l31) * 264 + ks * 16 + half * 8);
            short8 bf1 = *(const short8*)(wbuf + (32 * g1n + l31) * 264 + ks * 16 + 16 + half * 8);
            ha = __builtin_amdgcn_mfma_f32_32x32x16_bf16(afrag[ks], bf0, ha, 0, 0, 0);
            hb = __builtin_amdgcn_mfma_f32_32x32x16_bf16(afrag[ks + 1], bf1, hb, 0, 0, 0);
        }
        {   // bias + GELU -> hbuf (packed converts)
            float bb = b1[ch * 64 + 32 * g1n + l31];
            int col = 32 * g1n + l31;
            #pragma unroll
            for (int r = 0; r < 16; r += 2) {
                float v0 = gelu_f(ha[r] + hb[r] + bb);
                float v1 = gelu_f(ha[r + 1] + hb[r + 1] + bb);
                unsigned int pk = f2bf2(v0, v1);
                int row0 = 32 * g1m + (r & 3) + 8 * (r >> 2) + 4 * half;
                hbuf[row0 * 72 + col]       = (ushort_t)pk;
                hbuf[(row0 + 1) * 72 + col] = (ushort_t)(pk >> 16);
            }
        }
        __syncthreads();                         // B1: w1 reads + hbuf writes done
        {
            #pragma unroll
            for (int j = 0; j < 9; ++j) wb16[j * 256 + t] = w2reg[j];
        }
        __syncthreads();                         // B2: wbuf = w2[ch]
        if (ch < 15) {   // prefetch w1[ch+1] (covered by GEMM2)
            const u32x4* s1 = (const u32x4*)(w1p + (size_t)(ch + 1) * 16896);
            #pragma unroll
            for (int j = 0; j < 8; ++j) w1reg[j] = s1[j * 256 + t];
            if (t < 64) w1reg[8] = s1[2048 + t];
        }
        // ---- GEMM2: out += H @ w2[ch]
        #pragma unroll
        for (int ks = 0; ks < 4; ++ks) {
            short8 haf = *(const short8*)(hbuf + (32 * g2m + l31) * 72 + ks * 16 + half * 8);
            #pragma unroll
            for (int nt = 0; nt < 4; ++nt) {
                short8 bfr = *(const short8*)(wbuf + (g2nb + 32 * nt + l31) * 72 + ks * 16 + half * 8);
                oacc[nt] = __builtin_amdgcn_mfma_f32_32x32x16_bf16(haf, bfr, oacc[nt], 0, 0, 0);
            }
        }
        __syncthreads();                         // B3: w2 + hbuf reads done
        if (ch < 15) {
            #pragma unroll
            for (int j = 0; j < 8; ++j) wb16[j * 256 + t] = w1reg[j];
            if (t < 64) wb16[2048 + t] = w1reg[8];
        }
        __syncthreads();                         // B4: wbuf = w1[ch+1]
    }

    // epilogue: + bm2 + x2 residual
    #pragma unroll
    for (int nt = 0; nt < 4; ++nt) {
        int col = g2nb + 32 * nt + l31;
        float bb = bm2[col];
        #pragma unroll
        for (int r = 0; r < 16; ++r) {
            int row = 32 * g2m + (r & 3) + 8 * (r >> 2) + 4 * half;
            oacc[nt][r] += bb + bf2f(x2_s[row * 264 + col]);
        }
    }
    __syncthreads();   // x2_s/wbuf dead -> ot_s overlay safe
    #pragma unroll
    for (int nt = 0; nt < 4; ++nt) {
        int col = g2nb + 32 * nt + l31;
        #pragma unroll
        for (int r = 0; r < 16; r += 2) {
            int row0 = 32 * g2m + (r & 3) + 8 * (r >> 2) + 4 * half;   // even
            *(unsigned int*)(ot_s + col * 72 + row0) = f2bf2(oacc[nt][r], oacc[nt][r + 1]);
        }
    }
    __syncthreads();
    {   // coalesced fp32 NCHW store: pixel-per-lane, channel per iteration
        for (int it = 0; it < 64; ++it) {
            int c = it * 4 + wv;
            out[(size_t)c * 65536 + p0 + lane] = bf2f(ot_s[c * 72 + lane]);
        }
    }
}

extern "C" void kernel_launch(void* const* d_in, const int* in_sizes, int n_in,
                              void* d_out, int out_size, void* d_ws, size_t ws_size,
                              hipStream_t stream) {
    (void)in_sizes; (void)n_in; (void)out_size; (void)ws_size;
    const float* x     = (const float*)d_in[0];
    const float* n1g   = (const float*)d_in[1];
    const float* n1b   = (const float*)d_in[2];
    const float* qkv_r = (const float*)d_in[3];
    const float* pr_w  = (const float*)d_in[4];
    const float* pr_b  = (const float*)d_in[5];
    const float* tab_r = (const float*)d_in[6];
    const float* qkv_a = (const float*)d_in[7];
    const float* pa_w  = (const float*)d_in[8];
    const float* pa_b  = (const float*)d_in[9];
    const float* tab_a = (const float*)d_in[10];
    const float* n2g   = (const float*)d_in[11];
    const float* n2b   = (const float*)d_in[12];
    const float* w1    = (const float*)d_in[13];
    const float* b1    = (const float*)d_in[14];
    const float* w2    = (const float*)d_in[15];
    const float* b2    = (const float*)d_in[16];

    char* ws = (char*)d_ws;
    ushort_t* wqkvT_r = (ushort_t*)(ws);              //  98304 B
    ushort_t* wqkvT_a = (ushort_t*)(ws + 98304);      //  98304 B
    ushort_t* wpT_r   = (ushort_t*)(ws + 196608);     //  32768 B
    ushort_t* wpT_a   = (ushort_t*)(ws + 229376);     //  32768 B
    ushort_t* w1p     = (ushort_t*)(ws + 262144);     // 540672 B  [16][64][264]
    ushort_t* w2p     = (ushort_t*)(ws + 802816);     // 589824 B  [16][256][72]
    ushort_t* bout    = (ushort_t*)(ws + 1392640);    // 33554432 B
    ushort_t* xn      = (ushort_t*)d_out;             // staged in d_out (dead before mlp_k)

    prep_k<<<1664, 256, 0, stream>>>(x, n1g, n1b, xn,
                                     qkv_r, wqkvT_r, qkv_a, wqkvT_a,
                                     pr_w, wpT_r, pa_w, wpT_a,
                                     w1, w1p, w2, w2p);
    attn_k<<<dim3(1024, 2), 256, 0, stream>>>(xn, wqkvT_r, wpT_r, pr_b, tab_r,
                                              wqkvT_a, wpT_a, pa_b, tab_a, bout);
    mlp_k<<<1024, 256, 0, stream>>>(x, bout, n2g, n2b, w1p, b1, w2p, b2, (float*)d_out);
}